// Round 11
// baseline (120.558 us; speedup 1.0000x reference)
//
#include <hip/hip_runtime.h>

typedef _Float16 f16x8 __attribute__((ext_vector_type(8)));
typedef float    f32x4 __attribute__((ext_vector_type(4)));
typedef float    f32x16 __attribute__((ext_vector_type(16)));
typedef unsigned int u32;

#define N_CTX 16384
#define N_Q   4096
#define DIM   100
#define THR   4.0f

union FragU { unsigned int u[4]; f16x8 v; };

#define MFMA32(a, b, c) __builtin_amdgcn_mfma_f32_32x32x16_f16((a), (b), (c), 0, 0, 0)
#define GLOAD_LDS(g, l) __builtin_amdgcn_global_load_lds( \
    (const __attribute__((address_space(1))) u32*)(const void*)(g), \
    (__attribute__((address_space(3))) u32*)(void*)(l), 16, 0, 0)

// ---------------- fused prep ----------------
// qbS: per 32-j block an 8KB image; element (j,d) at byte
//      (d>>3)*512 + (j&31)*16 + (d&7)*2.  d=100 -> t_j, d>100 -> 0.
// cbH: [16384][128] fp16 rows: d<100 -> ctx*w3, d==100 -> 1.0, else 0.  (+ a[i])
// qTS: per 32-j block an 8KB image; element (d, jl) at byte
//      (d>>5)*2048 + (jl>>3)*512 + (d&31)*16 + (jl&7)*2. d=100 row = ones.
// blocks 0..15 qbS+t | 16..79 cbH + a | 80..143 qTS
__global__ void prep_all(const float* __restrict__ q, const float* __restrict__ ctx,
                         const float* __restrict__ ker,
                         unsigned short* __restrict__ qbS, unsigned short* __restrict__ qTS,
                         unsigned short* __restrict__ cbH, float* __restrict__ a) {
    int b = blockIdx.x;
    int tid = threadIdx.x;
    if (b < 16) {
        int j = b * 256 + tid;
        const float* row = q + (size_t)j * DIM;
        float buf[100];
        float acc = 0.f;
        #pragma unroll
        for (int d4 = 0; d4 < 25; ++d4) {
            #pragma unroll
            for (int e = 0; e < 4; ++e) {
                float v = row[4 * d4 + e];
                buf[4 * d4 + e] = v;
                acc += v * ker[100 + 4 * d4 + e];
            }
        }
        char* img = (char*)qbS + (size_t)(j >> 5) * 8192 + (j & 31) * 16;
        #pragma unroll
        for (int o = 0; o < 16; ++o) {
            f16x8 h;
            #pragma unroll
            for (int e = 0; e < 8; ++e) {
                int d = 8 * o + e;
                float v = (d < DIM) ? buf[d] : (d == DIM ? acc : 0.f);
                h[e] = (_Float16)v;
            }
            *reinterpret_cast<f16x8*>(img + o * 512) = h;
        }
    } else if (b < 80) {
        int i = (b - 16) * 256 + tid;
        const float* row = ctx + (size_t)i * DIM;
        float buf[100];
        float acc = 0.f;
        #pragma unroll
        for (int d4 = 0; d4 < 25; ++d4) {
            #pragma unroll
            for (int e = 0; e < 4; ++e) {
                float v = row[4 * d4 + e];
                buf[4 * d4 + e] = v;
                acc += v * ker[4 * d4 + e];
            }
        }
        a[i] = acc;
        unsigned short* orow = cbH + (size_t)i * 128;
        #pragma unroll
        for (int c = 0; c < 16; ++c) {
            f16x8 h;
            #pragma unroll
            for (int e = 0; e < 8; ++e) {
                int d = 8 * c + e;
                float v = (d < DIM) ? buf[d] * ker[200 + d] : (d == DIM ? 1.f : 0.f);
                h[e] = (_Float16)v;
            }
            *reinterpret_cast<f16x8*>(orow + 8 * c) = h;
        }
    } else {
        __shared__ _Float16 ldsT[100][64];
        int j0 = (b - 80) * 64;
        int r = tid >> 2, c = tid & 3;
        const float* row = q + (size_t)(j0 + r) * DIM + c * 25;
        #pragma unroll
        for (int k = 0; k < 25; ++k) ldsT[c * 25 + k][r] = (_Float16)row[k];
        __syncthreads();
        #pragma unroll
        for (int k = 0; k < 4; ++k) {
            int ci = tid + k * 256;
            int jb = ci >> 9;
            int rem = ci & 511;
            int dt = rem >> 7, rem2 = rem & 127;
            int o = rem2 >> 5, rr = rem2 & 31;
            int d = dt * 32 + rr;
            f16x8 v;
            #pragma unroll
            for (int e = 0; e < 8; ++e) {
                int jl = jb * 32 + 8 * o + e;
                v[e] = (d < DIM) ? ldsT[d][jl] : (d == DIM ? (_Float16)1.f : (_Float16)0.f);
            }
            char* dst = (char*)qTS + (size_t)((j0 >> 5) + jb) * 8192
                        + dt * 2048 + o * 512 + rr * 16;
            *reinterpret_cast<f16x8*>(dst) = v;
        }
    }
}

// ---------------- main fused attention ----------------
__global__ __launch_bounds__(256, 4) void attn_main(
    const unsigned short* __restrict__ qbS, const unsigned short* __restrict__ qTS,
    const unsigned short* __restrict__ cbH,
    _Float16* __restrict__ Ub, float* __restrict__ mb,
    float* __restrict__ lb, float* __restrict__ mtb)
{
    __shared__ __align__(16) char stageMem[2][16384];

    const int tid  = threadIdx.x;
    const int w    = tid >> 6;
    const int lane = tid & 63;
    const int hi   = lane >> 5;
    const int c31  = lane & 31;
    const int it   = blockIdx.x;
    const int js   = blockIdx.y;
    const int JS   = gridDim.y;
    const int R    = (N_Q / 32) / JS;
    const int iw0  = it * 128 + w * 32;

    f16x8 cbF[7];
    {
        const unsigned short* crow = cbH + (size_t)(iw0 + c31) * 128 + 8 * hi;
        #pragma unroll
        for (int kk = 0; kk < 7; ++kk)
            cbF[kk] = *reinterpret_cast<const f16x8*>(crow + kk * 16);
    }

    f32x16 U0 = {}, U1 = {}, U2 = {}, U3 = {};
    float m = -INFINITY, mtrue = -INFINITY;

    const int bb0 = js * R;
    const int seg = w * 2;
    const int l16 = lane * 16;

    auto stage_fn = [&](int buf, int bb) {
        const char* gq = (const char*)qbS + (size_t)bb * 8192;
        const char* gt = (const char*)qTS + (size_t)bb * 8192;
        char* lq = stageMem[buf];
        #pragma unroll
        for (int k = 0; k < 2; ++k)
            GLOAD_LDS(gq + (seg + k) * 1024 + l16, lq + (seg + k) * 1024);
        #pragma unroll
        for (int k = 0; k < 2; ++k)
            GLOAD_LDS(gt + (seg + k) * 1024 + l16, lq + 8192 + (seg + k) * 1024);
    };

    stage_fn(0, bb0);
    __syncthreads();
    int cur = 0;

    for (int r = 0; r < R; ++r) {
        if (r + 1 < R) stage_fn(cur ^ 1, bb0 + r + 1);

        const char* qbL = stageMem[cur];
        const char* qTL = stageMem[cur] + 8192;

        // ---- QK^T (t folded at k=100), two accumulator chains ----
        f32x16 sa = {}, sb = {};
        __builtin_amdgcn_s_setprio(1);
        {
            f16x8 aq0 = *reinterpret_cast<const f16x8*>(qbL + 0 * 1024 + l16);
            f16x8 aq1 = *reinterpret_cast<const f16x8*>(qbL + 1 * 1024 + l16);
            f16x8 aq2 = *reinterpret_cast<const f16x8*>(qbL + 2 * 1024 + l16);
            f16x8 aq3 = *reinterpret_cast<const f16x8*>(qbL + 3 * 1024 + l16);
            f16x8 aq4 = *reinterpret_cast<const f16x8*>(qbL + 4 * 1024 + l16);
            f16x8 aq5 = *reinterpret_cast<const f16x8*>(qbL + 5 * 1024 + l16);
            f16x8 aq6 = *reinterpret_cast<const f16x8*>(qbL + 6 * 1024 + l16);
            sa = MFMA32(aq0, cbF[0], sa);
            sb = MFMA32(aq1, cbF[1], sb);
            sa = MFMA32(aq2, cbF[2], sa);
            sb = MFMA32(aq3, cbF[3], sb);
            sa = MFMA32(aq4, cbF[4], sa);
            sb = MFMA32(aq5, cbF[5], sb);
            sa = MFMA32(aq6, cbF[6], sa);
        }
        __builtin_amdgcn_s_setprio(0);

        float sc[16];
        #pragma unroll
        for (int q16 = 0; q16 < 16; ++q16) sc[q16] = sa[q16] + sb[q16];

        float t0 = fmaxf(sc[0], sc[1]),  t1 = fmaxf(sc[2], sc[3]);
        float t2 = fmaxf(sc[4], sc[5]),  t3 = fmaxf(sc[6], sc[7]);
        float t4 = fmaxf(sc[8], sc[9]),  t5 = fmaxf(sc[10], sc[11]);
        float t6 = fmaxf(sc[12], sc[13]), t7 = fmaxf(sc[14], sc[15]);
        t0 = fmaxf(t0, t1); t2 = fmaxf(t2, t3);
        t4 = fmaxf(t4, t5); t6 = fmaxf(t6, t7);
        float tm = fmaxf(fmaxf(t0, t2), fmaxf(t4, t6));
        mtrue = fmaxf(mtrue, tm);

        if (__any(tm > m + THR)) {
            float tmf = fmaxf(tm, __shfl_xor(tm, 32, 64));
            float mn = fmaxf(m, tmf);
            float scale = __expf(m - mn);
            U0 *= scale; U1 *= scale; U2 *= scale; U3 *= scale;
            m = mn;
        }

        #pragma unroll
        for (int q16 = 0; q16 < 16; ++q16) sc[q16] = __expf(sc[q16] - m);

        // ---- P -> PV B-operand (pkrtz pack + half exchange) ----
        unsigned int pk[8], pr[8];
        #pragma unroll
        for (int h2 = 0; h2 < 8; ++h2) {
            auto p2 = __builtin_amdgcn_cvt_pkrtz(sc[2 * h2], sc[2 * h2 + 1]);
            pk[h2] = __builtin_bit_cast(unsigned int, p2);
            pr[h2] = (unsigned int)__shfl_xor((int)pk[h2], 32, 64);
        }
        FragU f0, f1;
        f0.u[0] = hi ? pr[2] : pk[0];
        f0.u[1] = hi ? pr[3] : pk[1];
        f0.u[2] = hi ? pk[2] : pr[0];
        f0.u[3] = hi ? pk[3] : pr[1];
        f1.u[0] = hi ? pr[6] : pk[4];
        f1.u[1] = hi ? pr[7] : pk[5];
        f1.u[2] = hi ? pk[6] : pr[4];
        f1.u[3] = hi ? pk[7] : pr[5];

        // ---- PV ----
        __builtin_amdgcn_s_setprio(1);
        {
            f16x8 a0 = *reinterpret_cast<const f16x8*>(qTL + l16);
            f16x8 a1 = *reinterpret_cast<const f16x8*>(qTL + 1024 + l16);
            U0 = MFMA32(a0, f0.v, U0);
            U0 = MFMA32(a1, f1.v, U0);
        }
        {
            f16x8 a0 = *reinterpret_cast<const f16x8*>(qTL + 2048 + l16);
            f16x8 a1 = *reinterpret_cast<const f16x8*>(qTL + 3072 + l16);
            U1 = MFMA32(a0, f0.v, U1);
            U1 = MFMA32(a1, f1.v, U1);
        }
        {
            f16x8 a0 = *reinterpret_cast<const f16x8*>(qTL + 4096 + l16);
            f16x8 a1 = *reinterpret_cast<const f16x8*>(qTL + 5120 + l16);
            U2 = MFMA32(a0, f0.v, U2);
            U2 = MFMA32(a1, f1.v, U2);
        }
        {
            f16x8 a0 = *reinterpret_cast<const f16x8*>(qTL + 6144 + l16);
            f16x8 a1 = *reinterpret_cast<const f16x8*>(qTL + 7168 + l16);
            U3 = MFMA32(a0, f0.v, U3);
            U3 = MFMA32(a1, f1.v, U3);
        }
        __builtin_amdgcn_s_setprio(0);

        __syncthreads();
        cur ^= 1;
    }

    mtrue = fmaxf(mtrue, __shfl_xor(mtrue, 32, 64));
    float ltmp = __shfl_xor(U3[0], 32, 64);
    float lfull = hi ? U3[0] : ltmp;

    int irow = iw0 + c31;
    if (hi == 0) {
        mb [(size_t)js * N_CTX + irow] = m;
        lb [(size_t)js * N_CTX + irow] = lfull;
        mtb[(size_t)js * N_CTX + irow] = mtrue;
    }
    _Float16* ub = Ub + (((size_t)js * 128 + it) * DIM) * 128 + w * 32 + c31;
    #pragma unroll
    for (int r = 0; r < 16; ++r) {
        int dl = (r & 3) + 8 * (r >> 2) + 4 * hi;
        ub[(size_t)dl * 128]        = (_Float16)U0[r];
        ub[(size_t)(32 + dl) * 128] = (_Float16)U1[r];
        ub[(size_t)(64 + dl) * 128] = (_Float16)U2[r];
        if (96 + dl < DIM) ub[(size_t)(96 + dl) * 128] = (_Float16)U3[r];
    }
}

// ---------------- tail kernels ----------------

// mfull[i] = a[i] + max_js mtb[js][i]
template<int JS>
__global__ void kernel_mf(const float* __restrict__ a, const float* __restrict__ mtb,
                          float* __restrict__ mfull) {
    int i = blockIdx.x * 256 + threadIdx.x;
    float mt = -INFINITY;
    #pragma unroll
    for (int js = 0; js < JS; ++js) mt = fmaxf(mt, mtb[(size_t)js * N_CTX + i]);
    mfull[i] = a[i] + mt;
}

// redundant M/Z scan (L2-resident) + coalesced partial h for 64 rows
__global__ void kernel_h(const float* __restrict__ mfull, const float* __restrict__ ctx,
                         float* __restrict__ hp) {
    __shared__ float sm[256];
    __shared__ float smh[8][104];
    int t = threadIdx.x;
    float v = -INFINITY;
    for (int i = t; i < N_CTX; i += 256) v = fmaxf(v, mfull[i]);
    sm[t] = v; __syncthreads();
    for (int s = 128; s > 0; s >>= 1) { if (t < s) sm[t] = fmaxf(sm[t], sm[t + s]); __syncthreads(); }
    float M = sm[0];
    __syncthreads();
    float z = 0.f;
    for (int i = t; i < N_CTX; i += 256) z += __expf(mfull[i] - M);
    sm[t] = z; __syncthreads();
    for (int s = 128; s > 0; s >>= 1) { if (t < s) sm[t] += sm[t + s]; __syncthreads(); }
    float Z = sm[0];
    __syncthreads();

    int rr = t >> 5, d32 = t & 31;
    int i0 = blockIdx.x * 64;
    float a0 = 0.f, a1 = 0.f, a2 = 0.f, a3 = 0.f;
    for (int g = 0; g < 8; ++g) {
        int row = i0 + g * 8 + rr;
        float bw = __expf(mfull[row] - M);
        const float* cr = ctx + (size_t)row * DIM;
        a0 += bw * cr[d32];
        a1 += bw * cr[d32 + 32];
        a2 += bw * cr[d32 + 64];
        if (d32 < 4) a3 += bw * cr[d32 + 96];
    }
    smh[rr][d32]      = a0;
    smh[rr][d32 + 32] = a1;
    smh[rr][d32 + 64] = a2;
    if (d32 < 4) smh[rr][d32 + 96] = a3;
    __syncthreads();
    if (t < DIM) {
        float s = 0.f;
        #pragma unroll
        for (int g = 0; g < 8; ++g) s += smh[g][t];
        hp[blockIdx.x * 128 + t] = s / Z;
    }
}

// ---------------- combine: merge splits + inline h-reduce + write ALL 400 G cols ----
template<int JS>
__global__ __launch_bounds__(256, 4) void combine(
    const _Float16* __restrict__ Ub, const float* __restrict__ mb,
    const float* __restrict__ lb, const float* __restrict__ hp,
    const float* __restrict__ ctx, float* __restrict__ G)
{
    __shared__ float ctxL[32][100];
    __shared__ float uaL[32][100];
    __shared__ float hL[100];

    const int b   = blockIdx.x;
    const int tid = threadIdx.x;

    for (int idx = tid; idx < 32 * DIM; idx += 256) {
        int r = idx / DIM, d = idx - r * DIM;
        ctxL[r][d] = ctx[(size_t)(b * 32 + r) * DIM + d];
    }
    if (tid < DIM) {                           // inline hred (L2-resident hp)
        float s = 0.f;
        for (int bb = 0; bb < 256; ++bb) s += hp[bb * 128 + tid];
        hL[tid] = s;
    }
    __syncthreads();

    {
        int i32 = tid & 31, seg = tid >> 5;
        int row = b * 32 + i32;
        int iblk = row >> 7, il = row & 127;
        float mw[JS];
        float M = -INFINITY;
        #pragma unroll
        for (int js = 0; js < JS; ++js) {
            mw[js] = mb[(size_t)js * N_CTX + row];
            M = fmaxf(M, mw[js]);
        }
        float ew[JS];
        float L = 0.f;
        #pragma unroll
        for (int js = 0; js < JS; ++js) {
            ew[js] = __expf(mw[js] - M);
            L += lb[(size_t)js * N_CTX + row] * ew[js];
        }
        float invL = 1.f / L;
        for (int d = seg; d < DIM; d += 8) {
            float u = 0.f;
            #pragma unroll
            for (int js = 0; js < JS; ++js)
                u += (float)Ub[(((size_t)js * 128 + iblk) * DIM + d) * 128 + il] * ew[js];
            uaL[i32][d] = u * invL;
        }
    }
    __syncthreads();

    // linear coalesced sweep over 32 rows x 400 cols
    float* gOut = G + (size_t)b * 32 * 400;
    for (int idx = tid; idx < 32 * 400; idx += 256) {
        int r = idx / 400, c = idx - r * 400;
        int sel = c / 100, d = c - sel * 100;
        float cv = ctxL[r][d];
        float val;
        if (sel == 0)      val = cv;
        else if (sel == 1) val = uaL[r][d];
        else if (sel == 2) val = uaL[r][d] * cv;
        else               val = cv * hL[d];
        gOut[idx] = val;
    }
}

// ---------------- launcher ----------------
extern "C" void kernel_launch(void* const* d_in, const int* in_sizes, int n_in,
                              void* d_out, int out_size, void* d_ws, size_t ws_size,
                              hipStream_t stream) {
    const float* ctx = (const float*)d_in[0];
    const float* q   = (const float*)d_in[1];
    const float* ker = (const float*)d_in[2];
    float* G = (float*)d_out;

    char* ws = (char*)d_ws;
    unsigned short* qbS   = (unsigned short*)(ws);                 // 1,048,576
    unsigned short* qTS   = (unsigned short*)(ws + 1048576);       // 1,048,576
    unsigned short* cbH   = (unsigned short*)(ws + 2097152);       // 4,194,304
    float*          a     = (float*)(ws + 6291456);                // 65,536
    float*          mfull = (float*)(ws + 6356992);                // 65,536
    float*          hp    = (float*)(ws + 6422528);                // 131,072
    const size_t fixed = 6554112;

    int JS = 8;
    if (fixed + 8ull * 3473408ull > ws_size) JS = 4;
    if (fixed + 4ull * 3473408ull > ws_size) JS = 2;

    _Float16* Ub  = (_Float16*)(ws + fixed);
    size_t ubB    = (size_t)JS * 3276800ull;
    float*    mb  = (float*)(ws + fixed + ubB);
    float*    lb  = (float*)(ws + fixed + ubB + (size_t)JS * 65536ull);
    float*    mtb = (float*)(ws + fixed + ubB + (size_t)JS * 131072ull);

    prep_all<<<dim3(144), dim3(256), 0, stream>>>(q, ctx, ker, qbS, qTS, cbH, a);
    attn_main<<<dim3(128, JS), dim3(256), 0, stream>>>(qbS, qTS, cbH, Ub, mb, lb, mtb);

    if (JS == 8) {
        kernel_mf<8><<<dim3(64), dim3(256), 0, stream>>>(a, mtb, mfull);
        kernel_h<<<dim3(256), dim3(256), 0, stream>>>(mfull, ctx, hp);
        combine<8><<<dim3(512), dim3(256), 0, stream>>>(Ub, mb, lb, hp, ctx, G);
    } else if (JS == 4) {
        kernel_mf<4><<<dim3(64), dim3(256), 0, stream>>>(a, mtb, mfull);
        kernel_h<<<dim3(256), dim3(256), 0, stream>>>(mfull, ctx, hp);
        combine<4><<<dim3(512), dim3(256), 0, stream>>>(Ub, mb, lb, hp, ctx, G);
    } else {
        kernel_mf<2><<<dim3(64), dim3(256), 0, stream>>>(a, mtb, mfull);
        kernel_h<<<dim3(256), dim3(256), 0, stream>>>(mfull, ctx, hp);
        combine<2><<<dim3(512), dim3(256), 0, stream>>>(Ub, mb, lb, hp, ctx, G);
    }
}

// Round 12
// 111.336 us; speedup vs baseline: 1.0828x; 1.0828x over previous
//
#include <hip/hip_runtime.h>

typedef _Float16 f16x8 __attribute__((ext_vector_type(8)));
typedef float    f32x4 __attribute__((ext_vector_type(4)));
typedef float    f32x16 __attribute__((ext_vector_type(16)));
typedef unsigned int u32;

#define N_CTX 16384
#define N_Q   4096
#define DIM   100
#define THR   4.0f

union FragU { unsigned int u[4]; f16x8 v; };

#define MFMA32(a, b, c) __builtin_amdgcn_mfma_f32_32x32x16_f16((a), (b), (c), 0, 0, 0)
#define GLOAD_LDS(g, l) __builtin_amdgcn_global_load_lds( \
    (const __attribute__((address_space(1))) u32*)(const void*)(g), \
    (__attribute__((address_space(3))) u32*)(void*)(l), 16, 0, 0)

// ---------------- fused prep ----------------
// qbS: per 32-j block an 8KB image; element (j,d) at byte
//      (d>>3)*512 + (j&31)*16 + (d&7)*2.  d=100 -> t_j, d>100 -> 0.
// cbH: [16384][128] fp16 rows: d<100 -> ctx*w3, d==100 -> 1.0, else 0.  (+ a[i])
// qTS: per 32-j block an 8KB image; element (d, jl) at byte
//      (d>>5)*2048 + (jl>>3)*512 + (d&31)*16 + (jl&7)*2. d=100 row = ones.
// blocks 0..15 qbS+t | 16..79 cbH + a | 80..143 qTS
__global__ void prep_all(const float* __restrict__ q, const float* __restrict__ ctx,
                         const float* __restrict__ ker,
                         unsigned short* __restrict__ qbS, unsigned short* __restrict__ qTS,
                         unsigned short* __restrict__ cbH, float* __restrict__ a) {
    int b = blockIdx.x;
    int tid = threadIdx.x;
    if (b < 16) {
        int j = b * 256 + tid;
        const float* row = q + (size_t)j * DIM;
        float buf[100];
        float acc = 0.f;
        #pragma unroll
        for (int d4 = 0; d4 < 25; ++d4) {
            #pragma unroll
            for (int e = 0; e < 4; ++e) {
                float v = row[4 * d4 + e];
                buf[4 * d4 + e] = v;
                acc += v * ker[100 + 4 * d4 + e];
            }
        }
        char* img = (char*)qbS + (size_t)(j >> 5) * 8192 + (j & 31) * 16;
        #pragma unroll
        for (int o = 0; o < 16; ++o) {
            f16x8 h;
            #pragma unroll
            for (int e = 0; e < 8; ++e) {
                int d = 8 * o + e;
                float v = (d < DIM) ? buf[d] : (d == DIM ? acc : 0.f);
                h[e] = (_Float16)v;
            }
            *reinterpret_cast<f16x8*>(img + o * 512) = h;
        }
    } else if (b < 80) {
        int i = (b - 16) * 256 + tid;
        const float* row = ctx + (size_t)i * DIM;
        float buf[100];
        float acc = 0.f;
        #pragma unroll
        for (int d4 = 0; d4 < 25; ++d4) {
            #pragma unroll
            for (int e = 0; e < 4; ++e) {
                float v = row[4 * d4 + e];
                buf[4 * d4 + e] = v;
                acc += v * ker[4 * d4 + e];
            }
        }
        a[i] = acc;
        unsigned short* orow = cbH + (size_t)i * 128;
        #pragma unroll
        for (int c = 0; c < 16; ++c) {
            f16x8 h;
            #pragma unroll
            for (int e = 0; e < 8; ++e) {
                int d = 8 * c + e;
                float v = (d < DIM) ? buf[d] * ker[200 + d] : (d == DIM ? 1.f : 0.f);
                h[e] = (_Float16)v;
            }
            *reinterpret_cast<f16x8*>(orow + 8 * c) = h;
        }
    } else {
        __shared__ _Float16 ldsT[100][64];
        int j0 = (b - 80) * 64;
        int r = tid >> 2, c = tid & 3;
        const float* row = q + (size_t)(j0 + r) * DIM + c * 25;
        #pragma unroll
        for (int k = 0; k < 25; ++k) ldsT[c * 25 + k][r] = (_Float16)row[k];
        __syncthreads();
        #pragma unroll
        for (int k = 0; k < 4; ++k) {
            int ci = tid + k * 256;
            int jb = ci >> 9;
            int rem = ci & 511;
            int dt = rem >> 7, rem2 = rem & 127;
            int o = rem2 >> 5, rr = rem2 & 31;
            int d = dt * 32 + rr;
            f16x8 v;
            #pragma unroll
            for (int e = 0; e < 8; ++e) {
                int jl = jb * 32 + 8 * o + e;
                v[e] = (d < DIM) ? ldsT[d][jl] : (d == DIM ? (_Float16)1.f : (_Float16)0.f);
            }
            char* dst = (char*)qTS + (size_t)((j0 >> 5) + jb) * 8192
                        + dt * 2048 + o * 512 + rr * 16;
            *reinterpret_cast<f16x8*>(dst) = v;
        }
    }
}

// ---------------- main fused attention (round-10 main loop, verbatim) ----------------
__global__ __launch_bounds__(256, 4) void attn_main(
    const unsigned short* __restrict__ qbS, const unsigned short* __restrict__ qTS,
    const unsigned short* __restrict__ cbH,
    _Float16* __restrict__ Ub, float* __restrict__ mb,
    float* __restrict__ lb, float* __restrict__ mtb)
{
    __shared__ __align__(16) char stageMem[2][16384];

    const int tid  = threadIdx.x;
    const int w    = tid >> 6;
    const int lane = tid & 63;
    const int hi   = lane >> 5;
    const int c31  = lane & 31;
    const int it   = blockIdx.x;
    const int js   = blockIdx.y;
    const int JS   = gridDim.y;
    const int R    = (N_Q / 32) / JS;
    const int iw0  = it * 128 + w * 32;

    f16x8 cbF[7];
    {
        const unsigned short* crow = cbH + (size_t)(iw0 + c31) * 128 + 8 * hi;
        #pragma unroll
        for (int kk = 0; kk < 7; ++kk)
            cbF[kk] = *reinterpret_cast<const f16x8*>(crow + kk * 16);
    }

    f32x16 U0 = {}, U1 = {}, U2 = {}, U3 = {};
    float m = -INFINITY, mtrue = -INFINITY;

    const int bb0 = js * R;
    const int seg = w * 2;
    const int l16 = lane * 16;

    auto stage_fn = [&](int buf, int bb) {
        const char* gq = (const char*)qbS + (size_t)bb * 8192;
        const char* gt = (const char*)qTS + (size_t)bb * 8192;
        char* lq = stageMem[buf];
        #pragma unroll
        for (int k = 0; k < 2; ++k)
            GLOAD_LDS(gq + (seg + k) * 1024 + l16, lq + (seg + k) * 1024);
        #pragma unroll
        for (int k = 0; k < 2; ++k)
            GLOAD_LDS(gt + (seg + k) * 1024 + l16, lq + 8192 + (seg + k) * 1024);
    };

    stage_fn(0, bb0);
    __syncthreads();
    int cur = 0;

    for (int r = 0; r < R; ++r) {
        if (r + 1 < R) stage_fn(cur ^ 1, bb0 + r + 1);

        const char* qbL = stageMem[cur];
        const char* qTL = stageMem[cur] + 8192;

        // ---- QK^T (t folded at k=100), single accumulator chain ----
        f32x16 sacc = {};
        __builtin_amdgcn_s_setprio(1);
        #pragma unroll
        for (int kk = 0; kk < 7; ++kk) {
            f16x8 aq = *reinterpret_cast<const f16x8*>(qbL + kk * 1024 + l16);
            sacc = MFMA32(aq, cbF[kk], sacc);
        }
        __builtin_amdgcn_s_setprio(0);

        float sc[16];
        #pragma unroll
        for (int q16 = 0; q16 < 16; ++q16) sc[q16] = sacc[q16];

        float t0 = fmaxf(sc[0], sc[1]),  t1 = fmaxf(sc[2], sc[3]);
        float t2 = fmaxf(sc[4], sc[5]),  t3 = fmaxf(sc[6], sc[7]);
        float t4 = fmaxf(sc[8], sc[9]),  t5 = fmaxf(sc[10], sc[11]);
        float t6 = fmaxf(sc[12], sc[13]), t7 = fmaxf(sc[14], sc[15]);
        t0 = fmaxf(t0, t1); t2 = fmaxf(t2, t3);
        t4 = fmaxf(t4, t5); t6 = fmaxf(t6, t7);
        float tm = fmaxf(fmaxf(t0, t2), fmaxf(t4, t6));
        mtrue = fmaxf(mtrue, tm);

        if (__any(tm > m + THR)) {
            float tmf = fmaxf(tm, __shfl_xor(tm, 32, 64));
            float mn = fmaxf(m, tmf);
            float scale = __expf(m - mn);
            U0 *= scale; U1 *= scale; U2 *= scale; U3 *= scale;
            m = mn;
        }

        #pragma unroll
        for (int q16 = 0; q16 < 16; ++q16) sc[q16] = __expf(sc[q16] - m);

        // ---- P -> PV B-operand (pkrtz pack + half exchange) ----
        unsigned int pk[8], pr[8];
        #pragma unroll
        for (int h2 = 0; h2 < 8; ++h2) {
            auto p2 = __builtin_amdgcn_cvt_pkrtz(sc[2 * h2], sc[2 * h2 + 1]);
            pk[h2] = __builtin_bit_cast(unsigned int, p2);
            pr[h2] = (unsigned int)__shfl_xor((int)pk[h2], 32, 64);
        }
        FragU f0, f1;
        f0.u[0] = hi ? pr[2] : pk[0];
        f0.u[1] = hi ? pr[3] : pk[1];
        f0.u[2] = hi ? pk[2] : pr[0];
        f0.u[3] = hi ? pk[3] : pr[1];
        f1.u[0] = hi ? pr[6] : pk[4];
        f1.u[1] = hi ? pr[7] : pk[5];
        f1.u[2] = hi ? pk[6] : pr[4];
        f1.u[3] = hi ? pk[7] : pr[5];

        // ---- PV ----
        __builtin_amdgcn_s_setprio(1);
        {
            f16x8 a0 = *reinterpret_cast<const f16x8*>(qTL + l16);
            f16x8 a1 = *reinterpret_cast<const f16x8*>(qTL + 1024 + l16);
            U0 = MFMA32(a0, f0.v, U0);
            U0 = MFMA32(a1, f1.v, U0);
        }
        {
            f16x8 a0 = *reinterpret_cast<const f16x8*>(qTL + 2048 + l16);
            f16x8 a1 = *reinterpret_cast<const f16x8*>(qTL + 3072 + l16);
            U1 = MFMA32(a0, f0.v, U1);
            U1 = MFMA32(a1, f1.v, U1);
        }
        {
            f16x8 a0 = *reinterpret_cast<const f16x8*>(qTL + 4096 + l16);
            f16x8 a1 = *reinterpret_cast<const f16x8*>(qTL + 5120 + l16);
            U2 = MFMA32(a0, f0.v, U2);
            U2 = MFMA32(a1, f1.v, U2);
        }
        {
            f16x8 a0 = *reinterpret_cast<const f16x8*>(qTL + 6144 + l16);
            f16x8 a1 = *reinterpret_cast<const f16x8*>(qTL + 7168 + l16);
            U3 = MFMA32(a0, f0.v, U3);
            U3 = MFMA32(a1, f1.v, U3);
        }
        __builtin_amdgcn_s_setprio(0);

        __syncthreads();
        cur ^= 1;
    }

    mtrue = fmaxf(mtrue, __shfl_xor(mtrue, 32, 64));
    float ltmp = __shfl_xor(U3[0], 32, 64);
    float lfull = hi ? U3[0] : ltmp;

    int irow = iw0 + c31;
    if (hi == 0) {
        mb [(size_t)js * N_CTX + irow] = m;
        lb [(size_t)js * N_CTX + irow] = lfull;
        mtb[(size_t)js * N_CTX + irow] = mtrue;
    }
    _Float16* ub = Ub + (((size_t)js * 128 + it) * DIM) * 128 + w * 32 + c31;
    #pragma unroll
    for (int r = 0; r < 16; ++r) {
        int dl = (r & 3) + 8 * (r >> 2) + 4 * hi;
        ub[(size_t)dl * 128]        = (_Float16)U0[r];
        ub[(size_t)(32 + dl) * 128] = (_Float16)U1[r];
        ub[(size_t)(64 + dl) * 128] = (_Float16)U2[r];
        if (96 + dl < DIM) ub[(size_t)(96 + dl) * 128] = (_Float16)U3[r];
    }
}

// ---------------- tail kernels ----------------

// mfull[i] = a[i] + max_js mtb[js][i]
template<int JS>
__global__ void kernel_mf(const float* __restrict__ a, const float* __restrict__ mtb,
                          float* __restrict__ mfull) {
    int i = blockIdx.x * 256 + threadIdx.x;
    float mt = -INFINITY;
    #pragma unroll
    for (int js = 0; js < JS; ++js) mt = fmaxf(mt, mtb[(size_t)js * N_CTX + i]);
    mfull[i] = a[i] + mt;
}

// redundant M/Z scan (L2-resident) + coalesced partial h for 64 rows
__global__ void kernel_h(const float* __restrict__ mfull, const float* __restrict__ ctx,
                         float* __restrict__ hp) {
    __shared__ float sm[256];
    __shared__ float smh[8][104];
    int t = threadIdx.x;
    float v = -INFINITY;
    for (int i = t; i < N_CTX; i += 256) v = fmaxf(v, mfull[i]);
    sm[t] = v; __syncthreads();
    for (int s = 128; s > 0; s >>= 1) { if (t < s) sm[t] = fmaxf(sm[t], sm[t + s]); __syncthreads(); }
    float M = sm[0];
    __syncthreads();
    float z = 0.f;
    for (int i = t; i < N_CTX; i += 256) z += __expf(mfull[i] - M);
    sm[t] = z; __syncthreads();
    for (int s = 128; s > 0; s >>= 1) { if (t < s) sm[t] += sm[t + s]; __syncthreads(); }
    float Z = sm[0];
    __syncthreads();

    int rr = t >> 5, d32 = t & 31;
    int i0 = blockIdx.x * 64;
    float a0 = 0.f, a1 = 0.f, a2 = 0.f, a3 = 0.f;
    for (int g = 0; g < 8; ++g) {
        int row = i0 + g * 8 + rr;
        float bw = __expf(mfull[row] - M);
        const float* cr = ctx + (size_t)row * DIM;
        a0 += bw * cr[d32];
        a1 += bw * cr[d32 + 32];
        a2 += bw * cr[d32 + 64];
        if (d32 < 4) a3 += bw * cr[d32 + 96];
    }
    smh[rr][d32]      = a0;
    smh[rr][d32 + 32] = a1;
    smh[rr][d32 + 64] = a2;
    if (d32 < 4) smh[rr][d32 + 96] = a3;
    __syncthreads();
    if (t < DIM) {
        float s = 0.f;
        #pragma unroll
        for (int g = 0; g < 8; ++g) s += smh[g][t];
        hp[blockIdx.x * 128 + t] = s / Z;
    }
}

// ---------------- combine: merge splits + inline h-reduce + write ALL 400 G cols ----
template<int JS>
__global__ __launch_bounds__(256, 4) void combine(
    const _Float16* __restrict__ Ub, const float* __restrict__ mb,
    const float* __restrict__ lb, const float* __restrict__ hp,
    const float* __restrict__ ctx, float* __restrict__ G)
{
    __shared__ float ctxL[32][100];
    __shared__ float uaL[32][100];
    __shared__ float hL[100];

    const int b   = blockIdx.x;
    const int tid = threadIdx.x;

    for (int idx = tid; idx < 32 * DIM; idx += 256) {
        int r = idx / DIM, d = idx - r * DIM;
        ctxL[r][d] = ctx[(size_t)(b * 32 + r) * DIM + d];
    }
    if (tid < DIM) {                           // inline hred (L2-resident hp)
        float s = 0.f;
        for (int bb = 0; bb < 256; ++bb) s += hp[bb * 128 + tid];
        hL[tid] = s;
    }
    __syncthreads();

    {
        int i32 = tid & 31, seg = tid >> 5;
        int row = b * 32 + i32;
        int iblk = row >> 7, il = row & 127;
        float mw[JS];
        float M = -INFINITY;
        #pragma unroll
        for (int js = 0; js < JS; ++js) {
            mw[js] = mb[(size_t)js * N_CTX + row];
            M = fmaxf(M, mw[js]);
        }
        float ew[JS];
        float L = 0.f;
        #pragma unroll
        for (int js = 0; js < JS; ++js) {
            ew[js] = __expf(mw[js] - M);
            L += lb[(size_t)js * N_CTX + row] * ew[js];
        }
        float invL = 1.f / L;
        for (int d = seg; d < DIM; d += 8) {
            float u = 0.f;
            #pragma unroll
            for (int js = 0; js < JS; ++js)
                u += (float)Ub[(((size_t)js * 128 + iblk) * DIM + d) * 128 + il] * ew[js];
            uaL[i32][d] = u * invL;
        }
    }
    __syncthreads();

    // linear coalesced sweep over 32 rows x 400 cols
    float* gOut = G + (size_t)b * 32 * 400;
    for (int idx = tid; idx < 32 * 400; idx += 256) {
        int r = idx / 400, c = idx - r * 400;
        int sel = c / 100, d = c - sel * 100;
        float cv = ctxL[r][d];
        float val;
        if (sel == 0)      val = cv;
        else if (sel == 1) val = uaL[r][d];
        else if (sel == 2) val = uaL[r][d] * cv;
        else               val = cv * hL[d];
        gOut[idx] = val;
    }
}

// ---------------- launcher ----------------
extern "C" void kernel_launch(void* const* d_in, const int* in_sizes, int n_in,
                              void* d_out, int out_size, void* d_ws, size_t ws_size,
                              hipStream_t stream) {
    const float* ctx = (const float*)d_in[0];
    const float* q   = (const float*)d_in[1];
    const float* ker = (const float*)d_in[2];
    float* G = (float*)d_out;

    char* ws = (char*)d_ws;
    unsigned short* qbS   = (unsigned short*)(ws);                 // 1,048,576
    unsigned short* qTS   = (unsigned short*)(ws + 1048576);       // 1,048,576
    unsigned short* cbH   = (unsigned short*)(ws + 2097152);       // 4,194,304
    float*          a     = (float*)(ws + 6291456);                // 65,536
    float*          mfull = (float*)(ws + 6356992);                // 65,536
    float*          hp    = (float*)(ws + 6422528);                // 131,072
    const size_t fixed = 6554112;

    int JS = 8;
    if (fixed + 8ull * 3473408ull > ws_size) JS = 4;
    if (fixed + 4ull * 3473408ull > ws_size) JS = 2;

    _Float16* Ub  = (_Float16*)(ws + fixed);
    size_t ubB    = (size_t)JS * 3276800ull;
    float*    mb  = (float*)(ws + fixed + ubB);
    float*    lb  = (float*)(ws + fixed + ubB + (size_t)JS * 65536ull);
    float*    mtb = (float*)(ws + fixed + ubB + (size_t)JS * 131072ull);

    prep_all<<<dim3(144), dim3(256), 0, stream>>>(q, ctx, ker, qbS, qTS, cbH, a);
    attn_main<<<dim3(128, JS), dim3(256), 0, stream>>>(qbS, qTS, cbH, Ub, mb, lb, mtb);

    if (JS == 8) {
        kernel_mf<8><<<dim3(64), dim3(256), 0, stream>>>(a, mtb, mfull);
        kernel_h<<<dim3(256), dim3(256), 0, stream>>>(mfull, ctx, hp);
        combine<8><<<dim3(512), dim3(256), 0, stream>>>(Ub, mb, lb, hp, ctx, G);
    } else if (JS == 4) {
        kernel_mf<4><<<dim3(64), dim3(256), 0, stream>>>(a, mtb, mfull);
        kernel_h<<<dim3(256), dim3(256), 0, stream>>>(mfull, ctx, hp);
        combine<4><<<dim3(512), dim3(256), 0, stream>>>(Ub, mb, lb, hp, ctx, G);
    } else {
        kernel_mf<2><<<dim3(64), dim3(256), 0, stream>>>(a, mtb, mfull);
        kernel_h<<<dim3(256), dim3(256), 0, stream>>>(mfull, ctx, hp);
        combine<2><<<dim3(512), dim3(256), 0, stream>>>(Ub, mb, lb, hp, ctx, G);
    }
}

// Round 13
// 110.113 us; speedup vs baseline: 1.0949x; 1.0111x over previous
//
#include <hip/hip_runtime.h>

typedef _Float16 f16x8 __attribute__((ext_vector_type(8)));
typedef float    f32x4 __attribute__((ext_vector_type(4)));
typedef float    f32x16 __attribute__((ext_vector_type(16)));
typedef unsigned int u32;

#define N_CTX 16384
#define N_Q   4096
#define DIM   100
#define THR   5.7708f            // 4 nats in log2 units
#define LOG2E 1.4426950408889634f
#define LN2   0.6931471805599453f

union FragU { unsigned int u[4]; f16x8 v; };

#if __has_builtin(__builtin_amdgcn_exp2f)
#define EXP2(x) __builtin_amdgcn_exp2f(x)
#else
#define EXP2(x) exp2f(x)
#endif

#define MFMA32(a, b, c) __builtin_amdgcn_mfma_f32_32x32x16_f16((a), (b), (c), 0, 0, 0)
#define GLOAD_LDS(g, l) __builtin_amdgcn_global_load_lds( \
    (const __attribute__((address_space(1))) u32*)(const void*)(g), \
    (__attribute__((address_space(3))) u32*)(void*)(l), 16, 0, 0)

// ---------------- fused prep ----------------
// qbS: per 32-j block an 8KB image; element (j,d) at byte
//      (d>>3)*512 + (j&31)*16 + (d&7)*2.  Values PRE-SCALED by log2(e);
//      d=100 -> t_j*log2e, d>100 -> 0.
// cbH: [16384][128] fp16 rows: d<100 -> ctx*w3, d==100 -> 1.0, else 0.  (+ a[i])
// qTS: per 32-j block an 8KB image (UNSCALED); element (d, jl) at byte
//      (d>>5)*2048 + (jl>>3)*512 + (d&31)*16 + (jl&7)*2. d=100 row = ones.
// blocks 0..15 qbS+t | 16..79 cbH + a | 80..143 qTS
__global__ void prep_all(const float* __restrict__ q, const float* __restrict__ ctx,
                         const float* __restrict__ ker,
                         unsigned short* __restrict__ qbS, unsigned short* __restrict__ qTS,
                         unsigned short* __restrict__ cbH, float* __restrict__ a) {
    int b = blockIdx.x;
    int tid = threadIdx.x;
    if (b < 16) {
        int j = b * 256 + tid;
        const float* row = q + (size_t)j * DIM;
        float buf[100];
        float acc = 0.f;
        #pragma unroll
        for (int d4 = 0; d4 < 25; ++d4) {
            #pragma unroll
            for (int e = 0; e < 4; ++e) {
                float v = row[4 * d4 + e];
                buf[4 * d4 + e] = v;
                acc += v * ker[100 + 4 * d4 + e];
            }
        }
        char* img = (char*)qbS + (size_t)(j >> 5) * 8192 + (j & 31) * 16;
        #pragma unroll
        for (int o = 0; o < 16; ++o) {
            f16x8 h;
            #pragma unroll
            for (int e = 0; e < 8; ++e) {
                int d = 8 * o + e;
                float v = (d < DIM) ? buf[d] * LOG2E : (d == DIM ? acc * LOG2E : 0.f);
                h[e] = (_Float16)v;
            }
            *reinterpret_cast<f16x8*>(img + o * 512) = h;
        }
    } else if (b < 80) {
        int i = (b - 16) * 256 + tid;
        const float* row = ctx + (size_t)i * DIM;
        float buf[100];
        float acc = 0.f;
        #pragma unroll
        for (int d4 = 0; d4 < 25; ++d4) {
            #pragma unroll
            for (int e = 0; e < 4; ++e) {
                float v = row[4 * d4 + e];
                buf[4 * d4 + e] = v;
                acc += v * ker[4 * d4 + e];
            }
        }
        a[i] = acc;
        unsigned short* orow = cbH + (size_t)i * 128;
        #pragma unroll
        for (int c = 0; c < 16; ++c) {
            f16x8 h;
            #pragma unroll
            for (int e = 0; e < 8; ++e) {
                int d = 8 * c + e;
                float v = (d < DIM) ? buf[d] * ker[200 + d] : (d == DIM ? 1.f : 0.f);
                h[e] = (_Float16)v;
            }
            *reinterpret_cast<f16x8*>(orow + 8 * c) = h;
        }
    } else {
        __shared__ _Float16 ldsT[100][64];
        int j0 = (b - 80) * 64;
        int r = tid >> 2, c = tid & 3;
        const float* row = q + (size_t)(j0 + r) * DIM + c * 25;
        #pragma unroll
        for (int k = 0; k < 25; ++k) ldsT[c * 25 + k][r] = (_Float16)row[k];
        __syncthreads();
        #pragma unroll
        for (int k = 0; k < 4; ++k) {
            int ci = tid + k * 256;
            int jb = ci >> 9;
            int rem = ci & 511;
            int dt = rem >> 7, rem2 = rem & 127;
            int o = rem2 >> 5, rr = rem2 & 31;
            int d = dt * 32 + rr;
            f16x8 v;
            #pragma unroll
            for (int e = 0; e < 8; ++e) {
                int jl = jb * 32 + 8 * o + e;
                v[e] = (d < DIM) ? ldsT[d][jl] : (d == DIM ? (_Float16)1.f : (_Float16)0.f);
            }
            char* dst = (char*)qTS + (size_t)((j0 >> 5) + jb) * 8192
                        + dt * 2048 + o * 512 + rr * 16;
            *reinterpret_cast<f16x8*>(dst) = v;
        }
    }
}

// ---------------- main fused attention (log2-domain softmax) ----------------
__global__ __launch_bounds__(256, 4) void attn_main(
    const unsigned short* __restrict__ qbS, const unsigned short* __restrict__ qTS,
    const unsigned short* __restrict__ cbH,
    _Float16* __restrict__ Ub, float* __restrict__ mb,
    float* __restrict__ lb, float* __restrict__ mtb)
{
    __shared__ __align__(16) char stageMem[2][16384];

    const int tid  = threadIdx.x;
    const int w    = tid >> 6;
    const int lane = tid & 63;
    const int hi   = lane >> 5;
    const int c31  = lane & 31;
    const int it   = blockIdx.x;
    const int js   = blockIdx.y;
    const int JS   = gridDim.y;
    const int R    = (N_Q / 32) / JS;
    const int iw0  = it * 128 + w * 32;

    f16x8 cbF[7];
    {
        const unsigned short* crow = cbH + (size_t)(iw0 + c31) * 128 + 8 * hi;
        #pragma unroll
        for (int kk = 0; kk < 7; ++kk)
            cbF[kk] = *reinterpret_cast<const f16x8*>(crow + kk * 16);
    }

    f32x16 U0 = {}, U1 = {}, U2 = {}, U3 = {};
    float m = -INFINITY, mtrue = -INFINITY;    // in log2 units

    const int bb0 = js * R;
    const int seg = w * 2;
    const int l16 = lane * 16;

    auto stage_fn = [&](int buf, int bb) {
        const char* gq = (const char*)qbS + (size_t)bb * 8192;
        const char* gt = (const char*)qTS + (size_t)bb * 8192;
        char* lq = stageMem[buf];
        #pragma unroll
        for (int k = 0; k < 2; ++k)
            GLOAD_LDS(gq + (seg + k) * 1024 + l16, lq + (seg + k) * 1024);
        #pragma unroll
        for (int k = 0; k < 2; ++k)
            GLOAD_LDS(gt + (seg + k) * 1024 + l16, lq + 8192 + (seg + k) * 1024);
    };

    stage_fn(0, bb0);
    __syncthreads();
    int cur = 0;

    for (int r = 0; r < R; ++r) {
        if (r + 1 < R) stage_fn(cur ^ 1, bb0 + r + 1);

        const char* qbL = stageMem[cur];
        const char* qTL = stageMem[cur] + 8192;

        // ---- QK^T (t folded at k=100; output already in log2 units) ----
        f32x16 sacc = {};
        __builtin_amdgcn_s_setprio(1);
        #pragma unroll
        for (int kk = 0; kk < 7; ++kk) {
            f16x8 aq = *reinterpret_cast<const f16x8*>(qbL + kk * 1024 + l16);
            sacc = MFMA32(aq, cbF[kk], sacc);
        }
        __builtin_amdgcn_s_setprio(0);

        float sc[16];
        #pragma unroll
        for (int q16 = 0; q16 < 16; ++q16) sc[q16] = sacc[q16];

        // ---- tile max: v_max3 tree (8 ops) ----
        float x0 = fmaxf(fmaxf(sc[0],  sc[1]),  sc[2]);
        float x1 = fmaxf(fmaxf(sc[3],  sc[4]),  sc[5]);
        float x2 = fmaxf(fmaxf(sc[6],  sc[7]),  sc[8]);
        float x3 = fmaxf(fmaxf(sc[9],  sc[10]), sc[11]);
        float x4 = fmaxf(fmaxf(sc[12], sc[13]), sc[14]);
        float tm = fmaxf(fmaxf(fmaxf(x0, x1), x2), fmaxf(fmaxf(x3, x4), sc[15]));
        mtrue = fmaxf(mtrue, tm);

        if (__any(tm > m + THR)) {
            float tmf = fmaxf(tm, __shfl_xor(tm, 32, 64));
            float mn = fmaxf(m, tmf);
            float scale = EXP2(m - mn);
            U0 *= scale; U1 *= scale; U2 *= scale; U3 *= scale;
            m = mn;
        }

        #pragma unroll
        for (int q16 = 0; q16 < 16; ++q16) sc[q16] = EXP2(sc[q16] - m);

        // ---- P -> PV B-operand (pkrtz pack + half exchange) ----
        unsigned int pk[8], pr[8];
        #pragma unroll
        for (int h2 = 0; h2 < 8; ++h2) {
            auto p2 = __builtin_amdgcn_cvt_pkrtz(sc[2 * h2], sc[2 * h2 + 1]);
            pk[h2] = __builtin_bit_cast(unsigned int, p2);
            pr[h2] = (unsigned int)__shfl_xor((int)pk[h2], 32, 64);
        }
        FragU f0, f1;
        f0.u[0] = hi ? pr[2] : pk[0];
        f0.u[1] = hi ? pr[3] : pk[1];
        f0.u[2] = hi ? pk[2] : pr[0];
        f0.u[3] = hi ? pk[3] : pr[1];
        f1.u[0] = hi ? pr[6] : pk[4];
        f1.u[1] = hi ? pr[7] : pk[5];
        f1.u[2] = hi ? pk[6] : pr[4];
        f1.u[3] = hi ? pk[7] : pr[5];

        // ---- PV ----
        __builtin_amdgcn_s_setprio(1);
        {
            f16x8 a0 = *reinterpret_cast<const f16x8*>(qTL + l16);
            f16x8 a1 = *reinterpret_cast<const f16x8*>(qTL + 1024 + l16);
            U0 = MFMA32(a0, f0.v, U0);
            U0 = MFMA32(a1, f1.v, U0);
        }
        {
            f16x8 a0 = *reinterpret_cast<const f16x8*>(qTL + 2048 + l16);
            f16x8 a1 = *reinterpret_cast<const f16x8*>(qTL + 3072 + l16);
            U1 = MFMA32(a0, f0.v, U1);
            U1 = MFMA32(a1, f1.v, U1);
        }
        {
            f16x8 a0 = *reinterpret_cast<const f16x8*>(qTL + 4096 + l16);
            f16x8 a1 = *reinterpret_cast<const f16x8*>(qTL + 5120 + l16);
            U2 = MFMA32(a0, f0.v, U2);
            U2 = MFMA32(a1, f1.v, U2);
        }
        {
            f16x8 a0 = *reinterpret_cast<const f16x8*>(qTL + 6144 + l16);
            f16x8 a1 = *reinterpret_cast<const f16x8*>(qTL + 7168 + l16);
            U3 = MFMA32(a0, f0.v, U3);
            U3 = MFMA32(a1, f1.v, U3);
        }
        __builtin_amdgcn_s_setprio(0);

        __syncthreads();
        cur ^= 1;
    }

    mtrue = fmaxf(mtrue, __shfl_xor(mtrue, 32, 64));
    float ltmp = __shfl_xor(U3[0], 32, 64);
    float lfull = hi ? U3[0] : ltmp;

    int irow = iw0 + c31;
    if (hi == 0) {
        mb [(size_t)js * N_CTX + irow] = m;                 // log2 domain
        lb [(size_t)js * N_CTX + irow] = lfull;
        mtb[(size_t)js * N_CTX + irow] = mtrue * LN2;       // back to natural
    }
    _Float16* ub = Ub + (((size_t)js * 128 + it) * DIM) * 128 + w * 32 + c31;
    #pragma unroll
    for (int r = 0; r < 16; ++r) {
        int dl = (r & 3) + 8 * (r >> 2) + 4 * hi;
        ub[(size_t)dl * 128]        = (_Float16)U0[r];
        ub[(size_t)(32 + dl) * 128] = (_Float16)U1[r];
        ub[(size_t)(64 + dl) * 128] = (_Float16)U2[r];
        if (96 + dl < DIM) ub[(size_t)(96 + dl) * 128] = (_Float16)U3[r];
    }
}

// ---------------- tail kernels ----------------

// mfull[i] = a[i] + max_js mtb[js][i]   (natural domain)
template<int JS>
__global__ void kernel_mf(const float* __restrict__ a, const float* __restrict__ mtb,
                          float* __restrict__ mfull) {
    int i = blockIdx.x * 256 + threadIdx.x;
    float mt = -INFINITY;
    #pragma unroll
    for (int js = 0; js < JS; ++js) mt = fmaxf(mt, mtb[(size_t)js * N_CTX + i]);
    mfull[i] = a[i] + mt;
}

// redundant M/Z scan (L2-resident) + coalesced partial h for 64 rows
__global__ void kernel_h(const float* __restrict__ mfull, const float* __restrict__ ctx,
                         float* __restrict__ hp) {
    __shared__ float sm[256];
    __shared__ float smh[8][104];
    int t = threadIdx.x;
    float v = -INFINITY;
    for (int i = t; i < N_CTX; i += 256) v = fmaxf(v, mfull[i]);
    sm[t] = v; __syncthreads();
    for (int s = 128; s > 0; s >>= 1) { if (t < s) sm[t] = fmaxf(sm[t], sm[t + s]); __syncthreads(); }
    float M = sm[0];
    __syncthreads();
    float z = 0.f;
    for (int i = t; i < N_CTX; i += 256) z += __expf(mfull[i] - M);
    sm[t] = z; __syncthreads();
    for (int s = 128; s > 0; s >>= 1) { if (t < s) sm[t] += sm[t + s]; __syncthreads(); }
    float Z = sm[0];
    __syncthreads();

    int rr = t >> 5, d32 = t & 31;
    int i0 = blockIdx.x * 64;
    float a0 = 0.f, a1 = 0.f, a2 = 0.f, a3 = 0.f;
    for (int g = 0; g < 8; ++g) {
        int row = i0 + g * 8 + rr;
        float bw = __expf(mfull[row] - M);
        const float* cr = ctx + (size_t)row * DIM;
        a0 += bw * cr[d32];
        a1 += bw * cr[d32 + 32];
        a2 += bw * cr[d32 + 64];
        if (d32 < 4) a3 += bw * cr[d32 + 96];
    }
    smh[rr][d32]      = a0;
    smh[rr][d32 + 32] = a1;
    smh[rr][d32 + 64] = a2;
    if (d32 < 4) smh[rr][d32 + 96] = a3;
    __syncthreads();
    if (t < DIM) {
        float s = 0.f;
        #pragma unroll
        for (int g = 0; g < 8; ++g) s += smh[g][t];
        hp[blockIdx.x * 128 + t] = s / Z;
    }
}

// ---------------- combine: merge splits + inline h-reduce + write ALL 400 G cols ----
template<int JS>
__global__ __launch_bounds__(256, 4) void combine(
    const _Float16* __restrict__ Ub, const float* __restrict__ mb,
    const float* __restrict__ lb, const float* __restrict__ hp,
    const float* __restrict__ ctx, float* __restrict__ G)
{
    __shared__ float ctxL[32][100];
    __shared__ float uaL[32][100];
    __shared__ float hL[100];

    const int b   = blockIdx.x;
    const int tid = threadIdx.x;

    for (int idx = tid; idx < 32 * DIM; idx += 256) {
        int r = idx / DIM, d = idx - r * DIM;
        ctxL[r][d] = ctx[(size_t)(b * 32 + r) * DIM + d];
    }
    if (tid < DIM) {                           // inline hred (L2-resident hp)
        float s = 0.f;
        for (int bb = 0; bb < 256; ++bb) s += hp[bb * 128 + tid];
        hL[tid] = s;
    }
    __syncthreads();

    {
        int i32 = tid & 31, seg = tid >> 5;
        int row = b * 32 + i32;
        int iblk = row >> 7, il = row & 127;
        float mw[JS];
        float M = -INFINITY;
        #pragma unroll
        for (int js = 0; js < JS; ++js) {
            mw[js] = mb[(size_t)js * N_CTX + row];
            M = fmaxf(M, mw[js]);
        }
        float ew[JS];
        float L = 0.f;
        #pragma unroll
        for (int js = 0; js < JS; ++js) {
            ew[js] = EXP2(mw[js] - M);          // mb is log2-domain
            L += lb[(size_t)js * N_CTX + row] * ew[js];
        }
        float invL = 1.f / L;
        for (int d = seg; d < DIM; d += 8) {
            float u = 0.f;
            #pragma unroll
            for (int js = 0; js < JS; ++js)
                u += (float)Ub[(((size_t)js * 128 + iblk) * DIM + d) * 128 + il] * ew[js];
            uaL[i32][d] = u * invL;
        }
    }
    __syncthreads();

    // linear coalesced sweep over 32 rows x 400 cols
    float* gOut = G + (size_t)b * 32 * 400;
    for (int idx = tid; idx < 32 * 400; idx += 256) {
        int r = idx / 400, c = idx - r * 400;
        int sel = c / 100, d = c - sel * 100;
        float cv = ctxL[r][d];
        float val;
        if (sel == 0)      val = cv;
        else if (sel == 1) val = uaL[r][d];
        else if (sel == 2) val = uaL[r][d] * cv;
        else               val = cv * hL[d];
        gOut[idx] = val;
    }
}

// ---------------- launcher ----------------
extern "C" void kernel_launch(void* const* d_in, const int* in_sizes, int n_in,
                              void* d_out, int out_size, void* d_ws, size_t ws_size,
                              hipStream_t stream) {
    const float* ctx = (const float*)d_in[0];
    const float* q   = (const float*)d_in[1];
    const float* ker = (const float*)d_in[2];
    float* G = (float*)d_out;

    char* ws = (char*)d_ws;
    unsigned short* qbS   = (unsigned short*)(ws);                 // 1,048,576
    unsigned short* qTS   = (unsigned short*)(ws + 1048576);       // 1,048,576
    unsigned short* cbH   = (unsigned short*)(ws + 2097152);       // 4,194,304
    float*          a     = (float*)(ws + 6291456);                // 65,536
    float*          mfull = (float*)(ws + 6356992);                // 65,536
    float*          hp    = (float*)(ws + 6422528);                // 131,072
    const size_t fixed = 6554112;

    int JS = 8;
    if (fixed + 8ull * 3473408ull > ws_size) JS = 4;
    if (fixed + 4ull * 3473408ull > ws_size) JS = 2;

    _Float16* Ub  = (_Float16*)(ws + fixed);
    size_t ubB    = (size_t)JS * 3276800ull;
    float*    mb  = (float*)(ws + fixed + ubB);
    float*    lb  = (float*)(ws + fixed + ubB + (size_t)JS * 65536ull);
    float*    mtb = (float*)(ws + fixed + ubB + (size_t)JS * 131072ull);

    prep_all<<<dim3(144), dim3(256), 0, stream>>>(q, ctx, ker, qbS, qTS, cbH, a);
    attn_main<<<dim3(128, JS), dim3(256), 0, stream>>>(qbS, qTS, cbH, Ub, mb, lb, mtb);

    if (JS == 8) {
        kernel_mf<8><<<dim3(64), dim3(256), 0, stream>>>(a, mtb, mfull);
        kernel_h<<<dim3(256), dim3(256), 0, stream>>>(mfull, ctx, hp);
        combine<8><<<dim3(512), dim3(256), 0, stream>>>(Ub, mb, lb, hp, ctx, G);
    } else if (JS == 4) {
        kernel_mf<4><<<dim3(64), dim3(256), 0, stream>>>(a, mtb, mfull);
        kernel_h<<<dim3(256), dim3(256), 0, stream>>>(mfull, ctx, hp);
        combine<4><<<dim3(512), dim3(256), 0, stream>>>(Ub, mb, lb, hp, ctx, G);
    } else {
        kernel_mf<2><<<dim3(64), dim3(256), 0, stream>>>(a, mtb, mfull);
        kernel_h<<<dim3(256), dim3(256), 0, stream>>>(mfull, ctx, hp);
        combine<2><<<dim3(512), dim3(256), 0, stream>>>(Ub, mb, lb, hp, ctx, G);
    }
}

// Round 14
// 108.948 us; speedup vs baseline: 1.1066x; 1.0107x over previous
//
#include <hip/hip_runtime.h>

typedef _Float16 f16x8 __attribute__((ext_vector_type(8)));
typedef float    f32x4 __attribute__((ext_vector_type(4)));
typedef float    f32x16 __attribute__((ext_vector_type(16)));
typedef unsigned int u32;

#define N_CTX 16384
#define N_Q   4096
#define DIM   100
#define THR   5.7708f            // 4 nats in log2 units
#define LOG2E 1.4426950408889634f
#define LN2   0.6931471805599453f

union FragU { unsigned int u[4]; f16x8 v; };

#if __has_builtin(__builtin_amdgcn_exp2f)
#define EXP2(x) __builtin_amdgcn_exp2f(x)
#else
#define EXP2(x) exp2f(x)
#endif

#define MFMA32(a, b, c) __builtin_amdgcn_mfma_f32_32x32x16_f16((a), (b), (c), 0, 0, 0)
#define GLOAD_LDS(g, l) __builtin_amdgcn_global_load_lds( \
    (const __attribute__((address_space(1))) u32*)(const void*)(g), \
    (__attribute__((address_space(3))) u32*)(void*)(l), 16, 0, 0)

// ---------------- fused prep ----------------
// qbS: per 32-j block an 8KB image; q-row j is placed at SLOT s = perm(j&31)
//      (perm swaps 4-groups [4..7]<->[8..11] and [20..23]<->[24..27]; self-
//      inverse). Element (slot,d) at byte (d>>3)*512 + slot*16 + (d&7)*2.
//      Values PRE-SCALED by log2(e); d=100 -> t_j*log2e, d>100 -> 0.
//      The permutation makes the QK^T C-layout rows per lane-half coincide
//      with the PV B-operand's k-partition -> no cross-lane P exchange.
// cbH: [16384][128] fp16 rows: d<100 -> ctx*w3, d==100 -> 1.0, else 0.  (+ a[i])
// qTS: per 32-j block an 8KB image (UNSCALED, physical j order); element
//      (d, jl) at byte (d>>5)*2048 + (jl>>3)*512 + (d&31)*16 + (jl&7)*2.
//      d=100 row = ones.
// blocks 0..15 qbS+t | 16..79 cbH + a | 80..143 qTS
__global__ void prep_all(const float* __restrict__ q, const float* __restrict__ ctx,
                         const float* __restrict__ ker,
                         unsigned short* __restrict__ qbS, unsigned short* __restrict__ qTS,
                         unsigned short* __restrict__ cbH, float* __restrict__ a) {
    int b = blockIdx.x;
    int tid = threadIdx.x;
    if (b < 16) {
        int j = b * 256 + tid;
        const float* row = q + (size_t)j * DIM;
        float buf[100];
        float acc = 0.f;
        #pragma unroll
        for (int d4 = 0; d4 < 25; ++d4) {
            #pragma unroll
            for (int e = 0; e < 4; ++e) {
                float v = row[4 * d4 + e];
                buf[4 * d4 + e] = v;
                acc += v * ker[100 + 4 * d4 + e];
            }
        }
        int jl = j & 31;
        int g = jl >> 2, gm = g & 3;
        if (gm == 1 || gm == 2) g ^= 3;          // perm: swap groups 1<->2, 5<->6
        int slot = (g << 2) | (jl & 3);
        char* img = (char*)qbS + (size_t)(j >> 5) * 8192 + slot * 16;
        #pragma unroll
        for (int o = 0; o < 16; ++o) {
            f16x8 h;
            #pragma unroll
            for (int e = 0; e < 8; ++e) {
                int d = 8 * o + e;
                float v = (d < DIM) ? buf[d] * LOG2E : (d == DIM ? acc * LOG2E : 0.f);
                h[e] = (_Float16)v;
            }
            *reinterpret_cast<f16x8*>(img + o * 512) = h;
        }
    } else if (b < 80) {
        int i = (b - 16) * 256 + tid;
        const float* row = ctx + (size_t)i * DIM;
        float buf[100];
        float acc = 0.f;
        #pragma unroll
        for (int d4 = 0; d4 < 25; ++d4) {
            #pragma unroll
            for (int e = 0; e < 4; ++e) {
                float v = row[4 * d4 + e];
                buf[4 * d4 + e] = v;
                acc += v * ker[4 * d4 + e];
            }
        }
        a[i] = acc;
        unsigned short* orow = cbH + (size_t)i * 128;
        #pragma unroll
        for (int c = 0; c < 16; ++c) {
            f16x8 h;
            #pragma unroll
            for (int e = 0; e < 8; ++e) {
                int d = 8 * c + e;
                float v = (d < DIM) ? buf[d] * ker[200 + d] : (d == DIM ? 1.f : 0.f);
                h[e] = (_Float16)v;
            }
            *reinterpret_cast<f16x8*>(orow + 8 * c) = h;
        }
    } else {
        __shared__ _Float16 ldsT[100][64];
        int j0 = (b - 80) * 64;
        int r = tid >> 2, c = tid & 3;
        const float* row = q + (size_t)(j0 + r) * DIM + c * 25;
        #pragma unroll
        for (int k = 0; k < 25; ++k) ldsT[c * 25 + k][r] = (_Float16)row[k];
        __syncthreads();
        #pragma unroll
        for (int k = 0; k < 4; ++k) {
            int ci = tid + k * 256;
            int jb = ci >> 9;
            int rem = ci & 511;
            int dt = rem >> 7, rem2 = rem & 127;
            int o = rem2 >> 5, rr = rem2 & 31;
            int d = dt * 32 + rr;
            f16x8 v;
            #pragma unroll
            for (int e = 0; e < 8; ++e) {
                int jl = jb * 32 + 8 * o + e;
                v[e] = (d < DIM) ? ldsT[d][jl] : (d == DIM ? (_Float16)1.f : (_Float16)0.f);
            }
            char* dst = (char*)qTS + (size_t)((j0 >> 5) + jb) * 8192
                        + dt * 2048 + o * 512 + rr * 16;
            *reinterpret_cast<f16x8*>(dst) = v;
        }
    }
}

// ---------------- main fused attention (log2 softmax, shuffle-free P) ----------------
__global__ __launch_bounds__(256, 4) void attn_main(
    const unsigned short* __restrict__ qbS, const unsigned short* __restrict__ qTS,
    const unsigned short* __restrict__ cbH,
    _Float16* __restrict__ Ub, float* __restrict__ mb,
    float* __restrict__ lb, float* __restrict__ mtb)
{
    __shared__ __align__(16) char stageMem[2][16384];

    const int tid  = threadIdx.x;
    const int w    = tid >> 6;
    const int lane = tid & 63;
    const int hi   = lane >> 5;
    const int c31  = lane & 31;
    const int it   = blockIdx.x;
    const int js   = blockIdx.y;
    const int JS   = gridDim.y;
    const int R    = (N_Q / 32) / JS;
    const int iw0  = it * 128 + w * 32;

    f16x8 cbF[7];
    {
        const unsigned short* crow = cbH + (size_t)(iw0 + c31) * 128 + 8 * hi;
        #pragma unroll
        for (int kk = 0; kk < 7; ++kk)
            cbF[kk] = *reinterpret_cast<const f16x8*>(crow + kk * 16);
    }

    f32x16 U0 = {}, U1 = {}, U2 = {}, U3 = {};
    float m = -INFINITY, mtrue = -INFINITY;    // in log2 units

    const int bb0 = js * R;
    const int seg = w * 2;
    const int l16 = lane * 16;

    auto stage_fn = [&](int buf, int bb) {
        const char* gq = (const char*)qbS + (size_t)bb * 8192;
        const char* gt = (const char*)qTS + (size_t)bb * 8192;
        char* lq = stageMem[buf];
        #pragma unroll
        for (int k = 0; k < 2; ++k)
            GLOAD_LDS(gq + (seg + k) * 1024 + l16, lq + (seg + k) * 1024);
        #pragma unroll
        for (int k = 0; k < 2; ++k)
            GLOAD_LDS(gt + (seg + k) * 1024 + l16, lq + 8192 + (seg + k) * 1024);
    };

    stage_fn(0, bb0);
    __syncthreads();
    int cur = 0;

    for (int r = 0; r < R; ++r) {
        if (r + 1 < R) stage_fn(cur ^ 1, bb0 + r + 1);

        const char* qbL = stageMem[cur];
        const char* qTL = stageMem[cur] + 8192;

        // ---- QK^T (t folded at k=100; output in log2 units, j-permuted rows) ----
        f32x16 sacc = {};
        __builtin_amdgcn_s_setprio(1);
        #pragma unroll
        for (int kk = 0; kk < 7; ++kk) {
            f16x8 aq = *reinterpret_cast<const f16x8*>(qbL + kk * 1024 + l16);
            sacc = MFMA32(aq, cbF[kk], sacc);
        }
        __builtin_amdgcn_s_setprio(0);

        float sc[16];
        #pragma unroll
        for (int q16 = 0; q16 < 16; ++q16) sc[q16] = sacc[q16];

        // ---- tile max: v_max3 tree ----
        float x0 = fmaxf(fmaxf(sc[0],  sc[1]),  sc[2]);
        float x1 = fmaxf(fmaxf(sc[3],  sc[4]),  sc[5]);
        float x2 = fmaxf(fmaxf(sc[6],  sc[7]),  sc[8]);
        float x3 = fmaxf(fmaxf(sc[9],  sc[10]), sc[11]);
        float x4 = fmaxf(fmaxf(sc[12], sc[13]), sc[14]);
        float tm = fmaxf(fmaxf(fmaxf(x0, x1), x2), fmaxf(fmaxf(x3, x4), sc[15]));
        mtrue = fmaxf(mtrue, tm);

        if (__any(tm > m + THR)) {
            float tmf = fmaxf(tm, __shfl_xor(tm, 32, 64));
            float mn = fmaxf(m, tmf);
            float scale = EXP2(m - mn);
            U0 *= scale; U1 *= scale; U2 *= scale; U3 *= scale;
            m = mn;
        }

        #pragma unroll
        for (int q16 = 0; q16 < 16; ++q16) sc[q16] = EXP2(sc[q16] - m);

        // ---- P -> PV B-operand: direct pack (j-perm removed the exchange) ----
        FragU f0, f1;
        #pragma unroll
        for (int e2 = 0; e2 < 4; ++e2) {
            auto p0 = __builtin_amdgcn_cvt_pkrtz(sc[2 * e2],     sc[2 * e2 + 1]);
            auto p1 = __builtin_amdgcn_cvt_pkrtz(sc[8 + 2 * e2], sc[8 + 2 * e2 + 1]);
            f0.u[e2] = __builtin_bit_cast(unsigned int, p0);
            f1.u[e2] = __builtin_bit_cast(unsigned int, p1);
        }

        // ---- PV ----
        __builtin_amdgcn_s_setprio(1);
        {
            f16x8 a0 = *reinterpret_cast<const f16x8*>(qTL + l16);
            f16x8 a1 = *reinterpret_cast<const f16x8*>(qTL + 1024 + l16);
            U0 = MFMA32(a0, f0.v, U0);
            U0 = MFMA32(a1, f1.v, U0);
        }
        {
            f16x8 a0 = *reinterpret_cast<const f16x8*>(qTL + 2048 + l16);
            f16x8 a1 = *reinterpret_cast<const f16x8*>(qTL + 3072 + l16);
            U1 = MFMA32(a0, f0.v, U1);
            U1 = MFMA32(a1, f1.v, U1);
        }
        {
            f16x8 a0 = *reinterpret_cast<const f16x8*>(qTL + 4096 + l16);
            f16x8 a1 = *reinterpret_cast<const f16x8*>(qTL + 5120 + l16);
            U2 = MFMA32(a0, f0.v, U2);
            U2 = MFMA32(a1, f1.v, U2);
        }
        {
            f16x8 a0 = *reinterpret_cast<const f16x8*>(qTL + 6144 + l16);
            f16x8 a1 = *reinterpret_cast<const f16x8*>(qTL + 7168 + l16);
            U3 = MFMA32(a0, f0.v, U3);
            U3 = MFMA32(a1, f1.v, U3);
        }
        __builtin_amdgcn_s_setprio(0);

        __syncthreads();
        cur ^= 1;
    }

    mtrue = fmaxf(mtrue, __shfl_xor(mtrue, 32, 64));
    float ltmp = __shfl_xor(U3[0], 32, 64);
    float lfull = hi ? U3[0] : ltmp;

    int irow = iw0 + c31;
    if (hi == 0) {
        mb [(size_t)js * N_CTX + irow] = m;                 // log2 domain
        lb [(size_t)js * N_CTX + irow] = lfull;
        mtb[(size_t)js * N_CTX + irow] = mtrue * LN2;       // back to natural
    }
    _Float16* ub = Ub + (((size_t)js * 128 + it) * DIM) * 128 + w * 32 + c31;
    #pragma unroll
    for (int r = 0; r < 16; ++r) {
        int dl = (r & 3) + 8 * (r >> 2) + 4 * hi;
        ub[(size_t)dl * 128]        = (_Float16)U0[r];
        ub[(size_t)(32 + dl) * 128] = (_Float16)U1[r];
        ub[(size_t)(64 + dl) * 128] = (_Float16)U2[r];
        if (96 + dl < DIM) ub[(size_t)(96 + dl) * 128] = (_Float16)U3[r];
    }
}

// ---------------- tail kernels ----------------

// mfull[i] = a[i] + max_js mtb[js][i]   (natural domain)
template<int JS>
__global__ void kernel_mf(const float* __restrict__ a, const float* __restrict__ mtb,
                          float* __restrict__ mfull) {
    int i = blockIdx.x * 256 + threadIdx.x;
    float mt = -INFINITY;
    #pragma unroll
    for (int js = 0; js < JS; ++js) mt = fmaxf(mt, mtb[(size_t)js * N_CTX + i]);
    mfull[i] = a[i] + mt;
}

// redundant M/Z scan (L2-resident) + coalesced partial h for 64 rows
__global__ void kernel_h(const float* __restrict__ mfull, const float* __restrict__ ctx,
                         float* __restrict__ hp) {
    __shared__ float sm[256];
    __shared__ float smh[8][104];
    int t = threadIdx.x;
    float v = -INFINITY;
    for (int i = t; i < N_CTX; i += 256) v = fmaxf(v, mfull[i]);
    sm[t] = v; __syncthreads();
    for (int s = 128; s > 0; s >>= 1) { if (t < s) sm[t] = fmaxf(sm[t], sm[t + s]); __syncthreads(); }
    float M = sm[0];
    __syncthreads();
    float z = 0.f;
    for (int i = t; i < N_CTX; i += 256) z += __expf(mfull[i] - M);
    sm[t] = z; __syncthreads();
    for (int s = 128; s > 0; s >>= 1) { if (t < s) sm[t] += sm[t + s]; __syncthreads(); }
    float Z = sm[0];
    __syncthreads();

    int rr = t >> 5, d32 = t & 31;
    int i0 = blockIdx.x * 64;
    float a0 = 0.f, a1 = 0.f, a2 = 0.f, a3 = 0.f;
    for (int g = 0; g < 8; ++g) {
        int row = i0 + g * 8 + rr;
        float bw = __expf(mfull[row] - M);
        const float* cr = ctx + (size_t)row * DIM;
        a0 += bw * cr[d32];
        a1 += bw * cr[d32 + 32];
        a2 += bw * cr[d32 + 64];
        if (d32 < 4) a3 += bw * cr[d32 + 96];
    }
    smh[rr][d32]      = a0;
    smh[rr][d32 + 32] = a1;
    smh[rr][d32 + 64] = a2;
    if (d32 < 4) smh[rr][d32 + 96] = a3;
    __syncthreads();
    if (t < DIM) {
        float s = 0.f;
        #pragma unroll
        for (int g = 0; g < 8; ++g) s += smh[g][t];
        hp[blockIdx.x * 128 + t] = s / Z;
    }
}

// ---------------- combine: merge splits + inline h-reduce + write ALL 400 G cols ----
template<int JS>
__global__ __launch_bounds__(256, 4) void combine(
    const _Float16* __restrict__ Ub, const float* __restrict__ mb,
    const float* __restrict__ lb, const float* __restrict__ hp,
    const float* __restrict__ ctx, float* __restrict__ G)
{
    __shared__ float ctxL[32][100];
    __shared__ float uaL[32][100];
    __shared__ float hL[100];

    const int b   = blockIdx.x;
    const int tid = threadIdx.x;

    for (int idx = tid; idx < 32 * DIM; idx += 256) {
        int r = idx / DIM, d = idx - r * DIM;
        ctxL[r][d] = ctx[(size_t)(b * 32 + r) * DIM + d];
    }
    if (tid < DIM) {                           // inline hred (L2-resident hp)
        float s = 0.f;
        for (int bb = 0; bb < 256; ++bb) s += hp[bb * 128 + tid];
        hL[tid] = s;
    }
    __syncthreads();

    {
        int i32 = tid & 31, seg = tid >> 5;
        int row = b * 32 + i32;
        int iblk = row >> 7, il = row & 127;
        float mw[JS];
        float M = -INFINITY;
        #pragma unroll
        for (int js = 0; js < JS; ++js) {
            mw[js] = mb[(size_t)js * N_CTX + row];
            M = fmaxf(M, mw[js]);
        }
        float ew[JS];
        float L = 0.f;
        #pragma unroll
        for (int js = 0; js < JS; ++js) {
            ew[js] = EXP2(mw[js] - M);          // mb is log2-domain
            L += lb[(size_t)js * N_CTX + row] * ew[js];
        }
        float invL = 1.f / L;
        for (int d = seg; d < DIM; d += 8) {
            float u = 0.f;
            #pragma unroll
            for (int js = 0; js < JS; ++js)
                u += (float)Ub[(((size_t)js * 128 + iblk) * DIM + d) * 128 + il] * ew[js];
            uaL[i32][d] = u * invL;
        }
    }
    __syncthreads();

    // linear coalesced sweep over 32 rows x 400 cols
    float* gOut = G + (size_t)b * 32 * 400;
    for (int idx = tid; idx < 32 * 400; idx += 256) {
        int r = idx / 400, c = idx - r * 400;
        int sel = c / 100, d = c - sel * 100;
        float cv = ctxL[r][d];
        float val;
        if (sel == 0)      val = cv;
        else if (sel == 1) val = uaL[r][d];
        else if (sel == 2) val = uaL[r][d] * cv;
        else               val = cv * hL[d];
        gOut[idx] = val;
    }
}

// ---------------- launcher ----------------
extern "C" void kernel_launch(void* const* d_in, const int* in_sizes, int n_in,
                              void* d_out, int out_size, void* d_ws, size_t ws_size,
                              hipStream_t stream) {
    const float* ctx = (const float*)d_in[0];
    const float* q   = (const float*)d_in[1];
    const float* ker = (const float*)d_in[2];
    float* G = (float*)d_out;

    char* ws = (char*)d_ws;
    unsigned short* qbS   = (unsigned short*)(ws);                 // 1,048,576
    unsigned short* qTS   = (unsigned short*)(ws + 1048576);       // 1,048,576
    unsigned short* cbH   = (unsigned short*)(ws + 2097152);       // 4,194,304
    float*          a     = (float*)(ws + 6291456);                // 65,536
    float*          mfull = (float*)(ws + 6356992);                // 65,536
    float*          hp    = (float*)(ws + 6422528);                // 131,072
    const size_t fixed = 6554112;

    int JS = 8;
    if (fixed + 8ull * 3473408ull > ws_size) JS = 4;
    if (fixed + 4ull * 3473408ull > ws_size) JS = 2;

    _Float16* Ub  = (_Float16*)(ws + fixed);
    size_t ubB    = (size_t)JS * 3276800ull;
    float*    mb  = (float*)(ws + fixed + ubB);
    float*    lb  = (float*)(ws + fixed + ubB + (size_t)JS * 65536ull);
    float*    mtb = (float*)(ws + fixed + ubB + (size_t)JS * 131072ull);

    prep_all<<<dim3(144), dim3(256), 0, stream>>>(q, ctx, ker, qbS, qTS, cbH, a);
    attn_main<<<dim3(128, JS), dim3(256), 0, stream>>>(qbS, qTS, cbH, Ub, mb, lb, mtb);

    if (JS == 8) {
        kernel_mf<8><<<dim3(64), dim3(256), 0, stream>>>(a, mtb, mfull);
        kernel_h<<<dim3(256), dim3(256), 0, stream>>>(mfull, ctx, hp);
        combine<8><<<dim3(512), dim3(256), 0, stream>>>(Ub, mb, lb, hp, ctx, G);
    } else if (JS == 4) {
        kernel_mf<4><<<dim3(64), dim3(256), 0, stream>>>(a, mtb, mfull);
        kernel_h<<<dim3(256), dim3(256), 0, stream>>>(mfull, ctx, hp);
        combine<4><<<dim3(512), dim3(256), 0, stream>>>(Ub, mb, lb, hp, ctx, G);
    } else {
        kernel_mf<2><<<dim3(64), dim3(256), 0, stream>>>(a, mtb, mfull);
        kernel_h<<<dim3(256), dim3(256), 0, stream>>>(mfull, ctx, hp);
        combine<2><<<dim3(512), dim3(256), 0, stream>>>(Ub, mb, lb, hp, ctx, G);
    }
}

// Round 15
// 96.637 us; speedup vs baseline: 1.2475x; 1.1274x over previous
//
#include <hip/hip_runtime.h>

typedef _Float16 f16x8 __attribute__((ext_vector_type(8)));
typedef float    f32x4 __attribute__((ext_vector_type(4)));
typedef float    f32x16 __attribute__((ext_vector_type(16)));
typedef unsigned int u32;

#define N_CTX 16384
#define N_Q   4096
#define DIM   100
#define THR   5.7708f            // 4 nats in log2 units
#define LOG2E 1.4426950408889634f
#define LN2   0.6931471805599453f

union FragU { unsigned int u[4]; f16x8 v; };

#if __has_builtin(__builtin_amdgcn_exp2f)
#define EXP2(x) __builtin_amdgcn_exp2f(x)
#else
#define EXP2(x) exp2f(x)
#endif

#define MFMA32(a, b, c) __builtin_amdgcn_mfma_f32_32x32x16_f16((a), (b), (c), 0, 0, 0)
#define GLOAD_LDS(g, l) __builtin_amdgcn_global_load_lds( \
    (const __attribute__((address_space(1))) u32*)(const void*)(g), \
    (__attribute__((address_space(3))) u32*)(void*)(l), 16, 0, 0)

// ---------------- fused prep ----------------
// blocks 0..63  : Q pass — stages 64 q rows in LDS once, then writes BOTH
//                 qTS images AND (log2e-scaled, j-permuted) qbS images + t.
// blocks 64..127: ctx pass — cbH + a (one row per thread).
// Layouts identical to round 14.
__global__ void prep_all(const float* __restrict__ q, const float* __restrict__ ctx,
                         const float* __restrict__ ker,
                         unsigned short* __restrict__ qbS, unsigned short* __restrict__ qTS,
                         unsigned short* __restrict__ cbH, float* __restrict__ a) {
    int b = blockIdx.x;
    int tid = threadIdx.x;
    if (b < 64) {
        __shared__ _Float16 ldsT[100][64];
        __shared__ float tL[64];
        int j0 = b * 64;
        int r = tid >> 2, c = tid & 3;
        const float* row = q + (size_t)(j0 + r) * DIM + c * 25;
        float part = 0.f;
        #pragma unroll
        for (int k = 0; k < 25; ++k) {
            float v = row[k];
            ldsT[c * 25 + k][r] = (_Float16)v;
            part += v * ker[100 + c * 25 + k];
        }
        part += __shfl_xor(part, 1, 64);
        part += __shfl_xor(part, 2, 64);
        if (c == 0) tL[r] = part * LOG2E;
        __syncthreads();

        // qTS: 1024 chunks (2 images of 32 j)
        #pragma unroll
        for (int k = 0; k < 4; ++k) {
            int ci = tid + k * 256;
            int jb = ci >> 9;
            int rem = ci & 511;
            int dt = rem >> 7, rem2 = rem & 127;
            int o = rem2 >> 5, rr = rem2 & 31;
            int d = dt * 32 + rr;
            f16x8 v;
            #pragma unroll
            for (int e = 0; e < 8; ++e) {
                int jl = jb * 32 + 8 * o + e;
                v[e] = (d < DIM) ? ldsT[d][jl] : (d == DIM ? (_Float16)1.f : (_Float16)0.f);
            }
            char* dst = (char*)qTS + (size_t)((j0 >> 5) + jb) * 8192
                        + dt * 2048 + o * 512 + rr * 16;
            *reinterpret_cast<f16x8*>(dst) = v;
        }

        // qbS: 1024 chunks; chunk (jl, o): lane-consecutive jl, o fixed per wave
        #pragma unroll
        for (int k = 0; k < 4; ++k) {
            int ci = tid + k * 256;
            int jl = ci & 63;
            int o  = ci >> 6;
            int j5 = jl & 31;
            int g = j5 >> 2, gm = g & 3;
            if (gm == 1 || gm == 2) g ^= 3;          // perm: swap groups 1<->2, 5<->6
            int slot = (g << 2) | (j5 & 3);
            int img  = (j0 >> 5) + (jl >> 5);
            f16x8 h;
            #pragma unroll
            for (int e = 0; e < 8; ++e) {
                int d = 8 * o + e;
                float v = (d < DIM) ? (float)ldsT[d][jl] * LOG2E
                                    : (d == DIM ? tL[jl] : 0.f);
                h[e] = (_Float16)v;
            }
            *reinterpret_cast<f16x8*>((char*)qbS + (size_t)img * 8192 + o * 512 + slot * 16) = h;
        }
    } else {
        int i = (b - 64) * 256 + tid;
        const float* row = ctx + (size_t)i * DIM;
        float buf[100];
        float acc = 0.f;
        #pragma unroll
        for (int d4 = 0; d4 < 25; ++d4) {
            #pragma unroll
            for (int e = 0; e < 4; ++e) {
                float v = row[4 * d4 + e];
                buf[4 * d4 + e] = v;
                acc += v * ker[4 * d4 + e];
            }
        }
        a[i] = acc;
        unsigned short* orow = cbH + (size_t)i * 128;
        #pragma unroll
        for (int c = 0; c < 16; ++c) {
            f16x8 h;
            #pragma unroll
            for (int e = 0; e < 8; ++e) {
                int d = 8 * c + e;
                float v = (d < DIM) ? buf[d] * ker[200 + d] : (d == DIM ? 1.f : 0.f);
                h[e] = (_Float16)v;
            }
            *reinterpret_cast<f16x8*>(orow + 8 * c) = h;
        }
    }
}

// ---------------- main fused attention (unchanged from round 14) ----------------
__global__ __launch_bounds__(256, 4) void attn_main(
    const unsigned short* __restrict__ qbS, const unsigned short* __restrict__ qTS,
    const unsigned short* __restrict__ cbH,
    _Float16* __restrict__ Ub, float* __restrict__ mb,
    float* __restrict__ lb, float* __restrict__ mtb)
{
    __shared__ __align__(16) char stageMem[2][16384];

    const int tid  = threadIdx.x;
    const int w    = tid >> 6;
    const int lane = tid & 63;
    const int hi   = lane >> 5;
    const int c31  = lane & 31;
    const int it   = blockIdx.x;
    const int js   = blockIdx.y;
    const int JS   = gridDim.y;
    const int R    = (N_Q / 32) / JS;
    const int iw0  = it * 128 + w * 32;

    f16x8 cbF[7];
    {
        const unsigned short* crow = cbH + (size_t)(iw0 + c31) * 128 + 8 * hi;
        #pragma unroll
        for (int kk = 0; kk < 7; ++kk)
            cbF[kk] = *reinterpret_cast<const f16x8*>(crow + kk * 16);
    }

    f32x16 U0 = {}, U1 = {}, U2 = {}, U3 = {};
    float m = -INFINITY, mtrue = -INFINITY;    // in log2 units

    const int bb0 = js * R;
    const int seg = w * 2;
    const int l16 = lane * 16;

    auto stage_fn = [&](int buf, int bb) {
        const char* gq = (const char*)qbS + (size_t)bb * 8192;
        const char* gt = (const char*)qTS + (size_t)bb * 8192;
        char* lq = stageMem[buf];
        #pragma unroll
        for (int k = 0; k < 2; ++k)
            GLOAD_LDS(gq + (seg + k) * 1024 + l16, lq + (seg + k) * 1024);
        #pragma unroll
        for (int k = 0; k < 2; ++k)
            GLOAD_LDS(gt + (seg + k) * 1024 + l16, lq + 8192 + (seg + k) * 1024);
    };

    stage_fn(0, bb0);
    __syncthreads();
    int cur = 0;

    for (int r = 0; r < R; ++r) {
        if (r + 1 < R) stage_fn(cur ^ 1, bb0 + r + 1);

        const char* qbL = stageMem[cur];
        const char* qTL = stageMem[cur] + 8192;

        // ---- QK^T (t folded at k=100; log2 units, j-permuted rows) ----
        f32x16 sacc = {};
        __builtin_amdgcn_s_setprio(1);
        #pragma unroll
        for (int kk = 0; kk < 7; ++kk) {
            f16x8 aq = *reinterpret_cast<const f16x8*>(qbL + kk * 1024 + l16);
            sacc = MFMA32(aq, cbF[kk], sacc);
        }
        __builtin_amdgcn_s_setprio(0);

        float sc[16];
        #pragma unroll
        for (int q16 = 0; q16 < 16; ++q16) sc[q16] = sacc[q16];

        // ---- tile max: v_max3 tree ----
        float x0 = fmaxf(fmaxf(sc[0],  sc[1]),  sc[2]);
        float x1 = fmaxf(fmaxf(sc[3],  sc[4]),  sc[5]);
        float x2 = fmaxf(fmaxf(sc[6],  sc[7]),  sc[8]);
        float x3 = fmaxf(fmaxf(sc[9],  sc[10]), sc[11]);
        float x4 = fmaxf(fmaxf(sc[12], sc[13]), sc[14]);
        float tm = fmaxf(fmaxf(fmaxf(x0, x1), x2), fmaxf(fmaxf(x3, x4), sc[15]));
        mtrue = fmaxf(mtrue, tm);

        if (__any(tm > m + THR)) {
            float tmf = fmaxf(tm, __shfl_xor(tm, 32, 64));
            float mn = fmaxf(m, tmf);
            float scale = EXP2(m - mn);
            U0 *= scale; U1 *= scale; U2 *= scale; U3 *= scale;
            m = mn;
        }

        #pragma unroll
        for (int q16 = 0; q16 < 16; ++q16) sc[q16] = EXP2(sc[q16] - m);

        // ---- P -> PV B-operand: direct pack ----
        FragU f0, f1;
        #pragma unroll
        for (int e2 = 0; e2 < 4; ++e2) {
            auto p0 = __builtin_amdgcn_cvt_pkrtz(sc[2 * e2],     sc[2 * e2 + 1]);
            auto p1 = __builtin_amdgcn_cvt_pkrtz(sc[8 + 2 * e2], sc[8 + 2 * e2 + 1]);
            f0.u[e2] = __builtin_bit_cast(unsigned int, p0);
            f1.u[e2] = __builtin_bit_cast(unsigned int, p1);
        }

        // ---- PV ----
        __builtin_amdgcn_s_setprio(1);
        {
            f16x8 a0 = *reinterpret_cast<const f16x8*>(qTL + l16);
            f16x8 a1 = *reinterpret_cast<const f16x8*>(qTL + 1024 + l16);
            U0 = MFMA32(a0, f0.v, U0);
            U0 = MFMA32(a1, f1.v, U0);
        }
        {
            f16x8 a0 = *reinterpret_cast<const f16x8*>(qTL + 2048 + l16);
            f16x8 a1 = *reinterpret_cast<const f16x8*>(qTL + 3072 + l16);
            U1 = MFMA32(a0, f0.v, U1);
            U1 = MFMA32(a1, f1.v, U1);
        }
        {
            f16x8 a0 = *reinterpret_cast<const f16x8*>(qTL + 4096 + l16);
            f16x8 a1 = *reinterpret_cast<const f16x8*>(qTL + 5120 + l16);
            U2 = MFMA32(a0, f0.v, U2);
            U2 = MFMA32(a1, f1.v, U2);
        }
        {
            f16x8 a0 = *reinterpret_cast<const f16x8*>(qTL + 6144 + l16);
            f16x8 a1 = *reinterpret_cast<const f16x8*>(qTL + 7168 + l16);
            U3 = MFMA32(a0, f0.v, U3);
            U3 = MFMA32(a1, f1.v, U3);
        }
        __builtin_amdgcn_s_setprio(0);

        __syncthreads();
        cur ^= 1;
    }

    mtrue = fmaxf(mtrue, __shfl_xor(mtrue, 32, 64));
    float ltmp = __shfl_xor(U3[0], 32, 64);
    float lfull = hi ? U3[0] : ltmp;

    int irow = iw0 + c31;
    if (hi == 0) {
        mb [(size_t)js * N_CTX + irow] = m;                 // log2 domain
        lb [(size_t)js * N_CTX + irow] = lfull;
        mtb[(size_t)js * N_CTX + irow] = mtrue * LN2;       // natural domain
    }
    _Float16* ub = Ub + (((size_t)js * 128 + it) * DIM) * 128 + w * 32 + c31;
    #pragma unroll
    for (int r = 0; r < 16; ++r) {
        int dl = (r & 3) + 8 * (r >> 2) + 4 * hi;
        ub[(size_t)dl * 128]        = (_Float16)U0[r];
        ub[(size_t)(32 + dl) * 128] = (_Float16)U1[r];
        ub[(size_t)(64 + dl) * 128] = (_Float16)U2[r];
        if (96 + dl < DIM) ub[(size_t)(96 + dl) * 128] = (_Float16)U3[r];
    }
}

// ---------------- tail kernels ----------------

// mfull[i] = a[i] + max_js mtb[js][i]   (natural domain)
template<int JS>
__global__ void kernel_mf(const float* __restrict__ a, const float* __restrict__ mtb,
                          float* __restrict__ mfull) {
    int i = blockIdx.x * 256 + threadIdx.x;
    float mt = -INFINITY;
    #pragma unroll
    for (int js = 0; js < JS; ++js) mt = fmaxf(mt, mtb[(size_t)js * N_CTX + i]);
    mfull[i] = a[i] + mt;
}

// redundant M/Z scan (L2-resident) + coalesced partial h for 64 rows
__global__ void kernel_h(const float* __restrict__ mfull, const float* __restrict__ ctx,
                         float* __restrict__ hp) {
    __shared__ float sm[256];
    __shared__ float smh[8][104];
    int t = threadIdx.x;
    float v = -INFINITY;
    for (int i = t; i < N_CTX; i += 256) v = fmaxf(v, mfull[i]);
    sm[t] = v; __syncthreads();
    for (int s = 128; s > 0; s >>= 1) { if (t < s) sm[t] = fmaxf(sm[t], sm[t + s]); __syncthreads(); }
    float M = sm[0];
    __syncthreads();
    float z = 0.f;
    for (int i = t; i < N_CTX; i += 256) z += __expf(mfull[i] - M);
    sm[t] = z; __syncthreads();
    for (int s = 128; s > 0; s >>= 1) { if (t < s) sm[t] += sm[t + s]; __syncthreads(); }
    float Z = sm[0];
    __syncthreads();

    int rr = t >> 5, d32 = t & 31;
    int i0 = blockIdx.x * 64;
    float a0 = 0.f, a1 = 0.f, a2 = 0.f, a3 = 0.f;
    for (int g = 0; g < 8; ++g) {
        int row = i0 + g * 8 + rr;
        float bw = __expf(mfull[row] - M);
        const float* cr = ctx + (size_t)row * DIM;
        a0 += bw * cr[d32];
        a1 += bw * cr[d32 + 32];
        a2 += bw * cr[d32 + 64];
        if (d32 < 4) a3 += bw * cr[d32 + 96];
    }
    smh[rr][d32]      = a0;
    smh[rr][d32 + 32] = a1;
    smh[rr][d32 + 64] = a2;
    if (d32 < 4) smh[rr][d32 + 96] = a3;
    __syncthreads();
    if (t < DIM) {
        float s = 0.f;
        #pragma unroll
        for (int g = 0; g < 8; ++g) s += smh[g][t];
        hp[blockIdx.x * 128 + t] = s / Z;
    }
}

// ---------------- combine: merge splits + inline h-reduce + vectorized G sweep ----
template<int JS>
__global__ __launch_bounds__(256, 4) void combine(
    const _Float16* __restrict__ Ub, const float* __restrict__ mb,
    const float* __restrict__ lb, const float* __restrict__ hp,
    const float* __restrict__ ctx, float* __restrict__ G)
{
    __shared__ __align__(16) float ctxL[32][100];
    __shared__ __align__(16) float uaL[32][100];
    __shared__ __align__(16) float hL[100];

    const int b   = blockIdx.x;
    const int tid = threadIdx.x;

    // ctx stage: f32x4 chunks (32 rows x 25 chunks)
    for (int idx = tid; idx < 800; idx += 256) {
        int r = idx / 25, c4 = idx - r * 25;
        *reinterpret_cast<f32x4*>(&ctxL[r][c4 * 4]) =
            *reinterpret_cast<const f32x4*>(ctx + (size_t)(b * 32 + r) * DIM + c4 * 4);
    }
    if (tid < DIM) {                           // inline hred (L2-resident hp)
        float s = 0.f;
        for (int bb = 0; bb < 256; ++bb) s += hp[bb * 128 + tid];
        hL[tid] = s;
    }
    __syncthreads();

    {
        int i32 = tid & 31, seg = tid >> 5;
        int row = b * 32 + i32;
        int iblk = row >> 7, il = row & 127;
        float mw[JS];
        float M = -INFINITY;
        #pragma unroll
        for (int js = 0; js < JS; ++js) {
            mw[js] = mb[(size_t)js * N_CTX + row];
            M = fmaxf(M, mw[js]);
        }
        float ew[JS];
        float L = 0.f;
        #pragma unroll
        for (int js = 0; js < JS; ++js) {
            ew[js] = EXP2(mw[js] - M);          // mb is log2-domain
            L += lb[(size_t)js * N_CTX + row] * ew[js];
        }
        float invL = 1.f / L;
        for (int d = seg; d < DIM; d += 8) {
            float u = 0.f;
            #pragma unroll
            for (int js = 0; js < JS; ++js)
                u += (float)Ub[(((size_t)js * 128 + iblk) * DIM + d) * 128 + il] * ew[js];
            uaL[i32][d] = u * invL;
        }
    }
    __syncthreads();

    // vectorized coalesced sweep: 32 rows x 100 f32x4 chunks
    float* gOut = G + (size_t)b * 32 * 400;
    for (int idx = tid; idx < 3200; idx += 256) {
        int r = idx / 100, c4 = idx - r * 100;
        int sel = c4 / 25, d4 = (c4 - sel * 25) * 4;
        f32x4 cv = *reinterpret_cast<const f32x4*>(&ctxL[r][d4]);
        f32x4 out;
        if (sel == 0)      out = cv;
        else if (sel == 1) out = *reinterpret_cast<const f32x4*>(&uaL[r][d4]);
        else if (sel == 2) out = *reinterpret_cast<const f32x4*>(&uaL[r][d4]) * cv;
        else               out = cv * *reinterpret_cast<const f32x4*>(&hL[d4]);
        *reinterpret_cast<f32x4*>(gOut + (size_t)r * 400 + c4 * 4) = out;
    }
}

// ---------------- launcher ----------------
extern "C" void kernel_launch(void* const* d_in, const int* in_sizes, int n_in,
                              void* d_out, int out_size, void* d_ws, size_t ws_size,
                              hipStream_t stream) {
    const float* ctx = (const float*)d_in[0];
    const float* q   = (const float*)d_in[1];
    const float* ker = (const float*)d_in[2];
    float* G = (float*)d_out;

    char* ws = (char*)d_ws;
    unsigned short* qbS   = (unsigned short*)(ws);                 // 1,048,576
    unsigned short* qTS   = (unsigned short*)(ws + 1048576);       // 1,048,576
    unsigned short* cbH   = (unsigned short*)(ws + 2097152);       // 4,194,304
    float*          a     = (float*)(ws + 6291456);                // 65,536
    float*          mfull = (float*)(ws + 6356992);                // 65,536
    float*          hp    = (float*)(ws + 6422528);                // 131,072
    const size_t fixed = 6554112;

    int JS = 8;
    if (fixed + 8ull * 3473408ull > ws_size) JS = 4;
    if (fixed + 4ull * 3473408ull > ws_size) JS = 2;

    _Float16* Ub  = (_Float16*)(ws + fixed);
    size_t ubB    = (size_t)JS * 3276800ull;
    float*    mb  = (float*)(ws + fixed + ubB);
    float*    lb  = (float*)(ws + fixed + ubB + (size_t)JS * 65536ull);
    float*    mtb = (float*)(ws + fixed + ubB + (size_t)JS * 131072ull);

    prep_all<<<dim3(128), dim3(256), 0, stream>>>(q, ctx, ker, qbS, qTS, cbH, a);
    attn_main<<<dim3(128, JS), dim3(256), 0, stream>>>(qbS, qTS, cbH, Ub, mb, lb, mtb);

    if (JS == 8) {
        kernel_mf<8><<<dim3(64), dim3(256), 0, stream>>>(a, mtb, mfull);
        kernel_h<<<dim3(256), dim3(256), 0, stream>>>(mfull, ctx, hp);
        combine<8><<<dim3(512), dim3(256), 0, stream>>>(Ub, mb, lb, hp, ctx, G);
    } else if (JS == 4) {
        kernel_mf<4><<<dim3(64), dim3(256), 0, stream>>>(a, mtb, mfull);
        kernel_h<<<dim3(256), dim3(256), 0, stream>>>(mfull, ctx, hp);
        combine<4><<<dim3(512), dim3(256), 0, stream>>>(Ub, mb, lb, hp, ctx, G);
    } else {
        kernel_mf<2><<<dim3(64), dim3(256), 0, stream>>>(a, mtb, mfull);
        kernel_h<<<dim3(256), dim3(256), 0, stream>>>(mfull, ctx, hp);
        combine<2><<<dim3(512), dim3(256), 0, stream>>>(Ub, mb, lb, hp, ctx, G);
    }
}

// Round 16
// 89.189 us; speedup vs baseline: 1.3517x; 1.0835x over previous
//
#include <hip/hip_runtime.h>

typedef _Float16 f16x8 __attribute__((ext_vector_type(8)));
typedef float    f32x4 __attribute__((ext_vector_type(4)));
typedef float    f32x16 __attribute__((ext_vector_type(16)));
typedef unsigned int u32;

#define N_CTX 16384
#define N_Q   4096
#define DIM   100
#define THR   5.7708f            // 4 nats in log2 units
#define LOG2E 1.4426950408889634f
#define LN2   0.6931471805599453f

union FragU { unsigned int u[4]; f16x8 v; };

#if __has_builtin(__builtin_amdgcn_exp2f)
#define EXP2(x) __builtin_amdgcn_exp2f(x)
#else
#define EXP2(x) exp2f(x)
#endif

#define MFMA32(a, b, c) __builtin_amdgcn_mfma_f32_32x32x16_f16((a), (b), (c), 0, 0, 0)
#define GLOAD_LDS(g, l) __builtin_amdgcn_global_load_lds( \
    (const __attribute__((address_space(1))) u32*)(const void*)(g), \
    (__attribute__((address_space(3))) u32*)(void*)(l), 16, 0, 0)

// ---------------- fused prep (unchanged from round 15) ----------------
__global__ void prep_all(const float* __restrict__ q, const float* __restrict__ ctx,
                         const float* __restrict__ ker,
                         unsigned short* __restrict__ qbS, unsigned short* __restrict__ qTS,
                         unsigned short* __restrict__ cbH, float* __restrict__ a) {
    int b = blockIdx.x;
    int tid = threadIdx.x;
    if (b < 64) {
        __shared__ _Float16 ldsT[100][64];
        __shared__ float tL[64];
        int j0 = b * 64;
        int r = tid >> 2, c = tid & 3;
        const float* row = q + (size_t)(j0 + r) * DIM + c * 25;
        float part = 0.f;
        #pragma unroll
        for (int k = 0; k < 25; ++k) {
            float v = row[k];
            ldsT[c * 25 + k][r] = (_Float16)v;
            part += v * ker[100 + c * 25 + k];
        }
        part += __shfl_xor(part, 1, 64);
        part += __shfl_xor(part, 2, 64);
        if (c == 0) tL[r] = part * LOG2E;
        __syncthreads();

        #pragma unroll
        for (int k = 0; k < 4; ++k) {
            int ci = tid + k * 256;
            int jb = ci >> 9;
            int rem = ci & 511;
            int dt = rem >> 7, rem2 = rem & 127;
            int o = rem2 >> 5, rr = rem2 & 31;
            int d = dt * 32 + rr;
            f16x8 v;
            #pragma unroll
            for (int e = 0; e < 8; ++e) {
                int jl = jb * 32 + 8 * o + e;
                v[e] = (d < DIM) ? ldsT[d][jl] : (d == DIM ? (_Float16)1.f : (_Float16)0.f);
            }
            char* dst = (char*)qTS + (size_t)((j0 >> 5) + jb) * 8192
                        + dt * 2048 + o * 512 + rr * 16;
            *reinterpret_cast<f16x8*>(dst) = v;
        }

        #pragma unroll
        for (int k = 0; k < 4; ++k) {
            int ci = tid + k * 256;
            int jl = ci & 63;
            int o  = ci >> 6;
            int j5 = jl & 31;
            int g = j5 >> 2, gm = g & 3;
            if (gm == 1 || gm == 2) g ^= 3;          // perm: swap groups 1<->2, 5<->6
            int slot = (g << 2) | (j5 & 3);
            int img  = (j0 >> 5) + (jl >> 5);
            f16x8 h;
            #pragma unroll
            for (int e = 0; e < 8; ++e) {
                int d = 8 * o + e;
                float v = (d < DIM) ? (float)ldsT[d][jl] * LOG2E
                                    : (d == DIM ? tL[jl] : 0.f);
                h[e] = (_Float16)v;
            }
            *reinterpret_cast<f16x8*>((char*)qbS + (size_t)img * 8192 + o * 512 + slot * 16) = h;
        }
    } else {
        int i = (b - 64) * 256 + tid;
        const float* row = ctx + (size_t)i * DIM;
        float buf[100];
        float acc = 0.f;
        #pragma unroll
        for (int d4 = 0; d4 < 25; ++d4) {
            #pragma unroll
            for (int e = 0; e < 4; ++e) {
                float v = row[4 * d4 + e];
                buf[4 * d4 + e] = v;
                acc += v * ker[4 * d4 + e];
            }
        }
        a[i] = acc;
        unsigned short* orow = cbH + (size_t)i * 128;
        #pragma unroll
        for (int c = 0; c < 16; ++c) {
            f16x8 h;
            #pragma unroll
            for (int e = 0; e < 8; ++e) {
                int d = 8 * c + e;
                float v = (d < DIM) ? buf[d] * ker[200 + d] : (d == DIM ? 1.f : 0.f);
                h[e] = (_Float16)v;
            }
            *reinterpret_cast<f16x8*>(orow + 8 * c) = h;
        }
    }
}

// ---------------- main fused attention (unchanged from round 14/15) ----------------
__global__ __launch_bounds__(256, 4) void attn_main(
    const unsigned short* __restrict__ qbS, const unsigned short* __restrict__ qTS,
    const unsigned short* __restrict__ cbH,
    _Float16* __restrict__ Ub, float* __restrict__ mb,
    float* __restrict__ lb, float* __restrict__ mtb)
{
    __shared__ __align__(16) char stageMem[2][16384];

    const int tid  = threadIdx.x;
    const int w    = tid >> 6;
    const int lane = tid & 63;
    const int hi   = lane >> 5;
    const int c31  = lane & 31;
    const int it   = blockIdx.x;
    const int js   = blockIdx.y;
    const int JS   = gridDim.y;
    const int R    = (N_Q / 32) / JS;
    const int iw0  = it * 128 + w * 32;

    f16x8 cbF[7];
    {
        const unsigned short* crow = cbH + (size_t)(iw0 + c31) * 128 + 8 * hi;
        #pragma unroll
        for (int kk = 0; kk < 7; ++kk)
            cbF[kk] = *reinterpret_cast<const f16x8*>(crow + kk * 16);
    }

    f32x16 U0 = {}, U1 = {}, U2 = {}, U3 = {};
    float m = -INFINITY, mtrue = -INFINITY;    // in log2 units

    const int bb0 = js * R;
    const int seg = w * 2;
    const int l16 = lane * 16;

    auto stage_fn = [&](int buf, int bb) {
        const char* gq = (const char*)qbS + (size_t)bb * 8192;
        const char* gt = (const char*)qTS + (size_t)bb * 8192;
        char* lq = stageMem[buf];
        #pragma unroll
        for (int k = 0; k < 2; ++k)
            GLOAD_LDS(gq + (seg + k) * 1024 + l16, lq + (seg + k) * 1024);
        #pragma unroll
        for (int k = 0; k < 2; ++k)
            GLOAD_LDS(gt + (seg + k) * 1024 + l16, lq + 8192 + (seg + k) * 1024);
    };

    stage_fn(0, bb0);
    __syncthreads();
    int cur = 0;

    for (int r = 0; r < R; ++r) {
        if (r + 1 < R) stage_fn(cur ^ 1, bb0 + r + 1);

        const char* qbL = stageMem[cur];
        const char* qTL = stageMem[cur] + 8192;

        f32x16 sacc = {};
        __builtin_amdgcn_s_setprio(1);
        #pragma unroll
        for (int kk = 0; kk < 7; ++kk) {
            f16x8 aq = *reinterpret_cast<const f16x8*>(qbL + kk * 1024 + l16);
            sacc = MFMA32(aq, cbF[kk], sacc);
        }
        __builtin_amdgcn_s_setprio(0);

        float sc[16];
        #pragma unroll
        for (int q16 = 0; q16 < 16; ++q16) sc[q16] = sacc[q16];

        float x0 = fmaxf(fmaxf(sc[0],  sc[1]),  sc[2]);
        float x1 = fmaxf(fmaxf(sc[3],  sc[4]),  sc[5]);
        float x2 = fmaxf(fmaxf(sc[6],  sc[7]),  sc[8]);
        float x3 = fmaxf(fmaxf(sc[9],  sc[10]), sc[11]);
        float x4 = fmaxf(fmaxf(sc[12], sc[13]), sc[14]);
        float tm = fmaxf(fmaxf(fmaxf(x0, x1), x2), fmaxf(fmaxf(x3, x4), sc[15]));
        mtrue = fmaxf(mtrue, tm);

        if (__any(tm > m + THR)) {
            float tmf = fmaxf(tm, __shfl_xor(tm, 32, 64));
            float mn = fmaxf(m, tmf);
            float scale = EXP2(m - mn);
            U0 *= scale; U1 *= scale; U2 *= scale; U3 *= scale;
            m = mn;
        }

        #pragma unroll
        for (int q16 = 0; q16 < 16; ++q16) sc[q16] = EXP2(sc[q16] - m);

        FragU f0, f1;
        #pragma unroll
        for (int e2 = 0; e2 < 4; ++e2) {
            auto p0 = __builtin_amdgcn_cvt_pkrtz(sc[2 * e2],     sc[2 * e2 + 1]);
            auto p1 = __builtin_amdgcn_cvt_pkrtz(sc[8 + 2 * e2], sc[8 + 2 * e2 + 1]);
            f0.u[e2] = __builtin_bit_cast(unsigned int, p0);
            f1.u[e2] = __builtin_bit_cast(unsigned int, p1);
        }

        __builtin_amdgcn_s_setprio(1);
        {
            f16x8 a0 = *reinterpret_cast<const f16x8*>(qTL + l16);
            f16x8 a1 = *reinterpret_cast<const f16x8*>(qTL + 1024 + l16);
            U0 = MFMA32(a0, f0.v, U0);
            U0 = MFMA32(a1, f1.v, U0);
        }
        {
            f16x8 a0 = *reinterpret_cast<const f16x8*>(qTL + 2048 + l16);
            f16x8 a1 = *reinterpret_cast<const f16x8*>(qTL + 3072 + l16);
            U1 = MFMA32(a0, f0.v, U1);
            U1 = MFMA32(a1, f1.v, U1);
        }
        {
            f16x8 a0 = *reinterpret_cast<const f16x8*>(qTL + 4096 + l16);
            f16x8 a1 = *reinterpret_cast<const f16x8*>(qTL + 5120 + l16);
            U2 = MFMA32(a0, f0.v, U2);
            U2 = MFMA32(a1, f1.v, U2);
        }
        {
            f16x8 a0 = *reinterpret_cast<const f16x8*>(qTL + 6144 + l16);
            f16x8 a1 = *reinterpret_cast<const f16x8*>(qTL + 7168 + l16);
            U3 = MFMA32(a0, f0.v, U3);
            U3 = MFMA32(a1, f1.v, U3);
        }
        __builtin_amdgcn_s_setprio(0);

        __syncthreads();
        cur ^= 1;
    }

    mtrue = fmaxf(mtrue, __shfl_xor(mtrue, 32, 64));
    float ltmp = __shfl_xor(U3[0], 32, 64);
    float lfull = hi ? U3[0] : ltmp;

    int irow = iw0 + c31;
    if (hi == 0) {
        mb [(size_t)js * N_CTX + irow] = m;                 // log2 domain
        lb [(size_t)js * N_CTX + irow] = lfull;
        mtb[(size_t)js * N_CTX + irow] = mtrue * LN2;       // natural domain
    }
    _Float16* ub = Ub + (((size_t)js * 128 + it) * DIM) * 128 + w * 32 + c31;
    #pragma unroll
    for (int r = 0; r < 16; ++r) {
        int dl = (r & 3) + 8 * (r >> 2) + 4 * hi;
        ub[(size_t)dl * 128]        = (_Float16)U0[r];
        ub[(size_t)(32 + dl) * 128] = (_Float16)U1[r];
        ub[(size_t)(64 + dl) * 128] = (_Float16)U2[r];
        if (96 + dl < DIM) ub[(size_t)(96 + dl) * 128] = (_Float16)U3[r];
    }
}

// ---------------- tail kernels ----------------

// mfull[i] = a[i] + max_js mtb[js][i]; + per-block max Mp[64]
template<int JS>
__global__ void kernel_mf(const float* __restrict__ a, const float* __restrict__ mtb,
                          float* __restrict__ mfull, float* __restrict__ Mp) {
    __shared__ float sm[256];
    int t = threadIdx.x;
    int i = blockIdx.x * 256 + t;
    float mt = -INFINITY;
    #pragma unroll
    for (int js = 0; js < JS; ++js) mt = fmaxf(mt, mtb[(size_t)js * N_CTX + i]);
    float v = a[i] + mt;
    mfull[i] = v;
    sm[t] = v; __syncthreads();
    for (int s = 128; s > 0; s >>= 1) { if (t < s) sm[t] = fmaxf(sm[t], sm[t + s]); __syncthreads(); }
    if (t == 0) Mp[blockIdx.x] = sm[0];
}

// 64 blocks; slice-local scan only: raw h-numerator partials + z partials
__global__ void kernel_h(const float* __restrict__ mfull, const float* __restrict__ Mp,
                         const float* __restrict__ ctx,
                         float* __restrict__ hp, float* __restrict__ zp) {
    __shared__ float smh[8][104];
    __shared__ float smz[8];
    int t = threadIdx.x;
    float M = -INFINITY;
    #pragma unroll 8
    for (int k = 0; k < 64; ++k) M = fmaxf(M, Mp[k]);

    int rr = t >> 5, d32 = t & 31;
    int i0 = blockIdx.x * 256;
    float a0 = 0.f, a1 = 0.f, a2 = 0.f, a3 = 0.f, wz = 0.f;
    for (int g = 0; g < 32; ++g) {
        int row = i0 + g * 8 + rr;
        float bw = __expf(mfull[row] - M);
        const float* cr = ctx + (size_t)row * DIM;
        a0 += bw * cr[d32];
        a1 += bw * cr[d32 + 32];
        a2 += bw * cr[d32 + 64];
        if (d32 < 4) a3 += bw * cr[d32 + 96];
        wz += bw;
    }
    smh[rr][d32]      = a0;
    smh[rr][d32 + 32] = a1;
    smh[rr][d32 + 64] = a2;
    if (d32 < 4) smh[rr][d32 + 96] = a3;
    if (d32 == 0) smz[rr] = wz;
    __syncthreads();
    if (t < DIM) {
        float s = 0.f;
        #pragma unroll
        for (int g = 0; g < 8; ++g) s += smh[g][t];
        hp[blockIdx.x * DIM + t] = s;          // raw numerator
    }
    if (t == 0) {
        float z = 0.f;
        #pragma unroll
        for (int g = 0; g < 8; ++g) z += smz[g];
        zp[blockIdx.x] = z;
    }
}

// ---------------- combine: merge splits + reduce 64 h-partials + G sweep ----
template<int JS>
__global__ __launch_bounds__(256, 4) void combine(
    const _Float16* __restrict__ Ub, const float* __restrict__ mb,
    const float* __restrict__ lb, const float* __restrict__ hp,
    const float* __restrict__ zp, const float* __restrict__ ctx,
    float* __restrict__ G)
{
    __shared__ __align__(16) float ctxL[32][100];
    __shared__ __align__(16) float uaL[32][100];
    __shared__ __align__(16) float hL[100];

    const int b   = blockIdx.x;
    const int tid = threadIdx.x;

    for (int idx = tid; idx < 800; idx += 256) {
        int r = idx / 25, c4 = idx - r * 25;
        *reinterpret_cast<f32x4*>(&ctxL[r][c4 * 4]) =
            *reinterpret_cast<const f32x4*>(ctx + (size_t)(b * 32 + r) * DIM + c4 * 4);
    }
    if (tid < DIM) {
        float s = 0.f, z = 0.f;
        #pragma unroll 8
        for (int bb = 0; bb < 64; ++bb) { s += hp[bb * DIM + tid]; z += zp[bb]; }
        hL[tid] = s / z;
    }
    __syncthreads();

    {
        int i32 = tid & 31, seg = tid >> 5;
        int row = b * 32 + i32;
        int iblk = row >> 7, il = row & 127;
        float mw[JS];
        float M = -INFINITY;
        #pragma unroll
        for (int js = 0; js < JS; ++js) {
            mw[js] = mb[(size_t)js * N_CTX + row];
            M = fmaxf(M, mw[js]);
        }
        float ew[JS];
        float L = 0.f;
        #pragma unroll
        for (int js = 0; js < JS; ++js) {
            ew[js] = EXP2(mw[js] - M);          // mb is log2-domain
            L += lb[(size_t)js * N_CTX + row] * ew[js];
        }
        float invL = 1.f / L;
        for (int d = seg; d < DIM; d += 8) {
            float u = 0.f;
            #pragma unroll
            for (int js = 0; js < JS; ++js)
                u += (float)Ub[(((size_t)js * 128 + iblk) * DIM + d) * 128 + il] * ew[js];
            uaL[i32][d] = u * invL;
        }
    }
    __syncthreads();

    float* gOut = G + (size_t)b * 32 * 400;
    for (int idx = tid; idx < 3200; idx += 256) {
        int r = idx / 100, c4 = idx - r * 100;
        int sel = c4 / 25, d4 = (c4 - sel * 25) * 4;
        f32x4 cv = *reinterpret_cast<const f32x4*>(&ctxL[r][d4]);
        f32x4 out;
        if (sel == 0)      out = cv;
        else if (sel == 1) out = *reinterpret_cast<const f32x4*>(&uaL[r][d4]);
        else if (sel == 2) out = *reinterpret_cast<const f32x4*>(&uaL[r][d4]) * cv;
        else               out = cv * *reinterpret_cast<const f32x4*>(&hL[d4]);
        *reinterpret_cast<f32x4*>(gOut + (size_t)r * 400 + c4 * 4) = out;
    }
}

// ---------------- launcher ----------------
extern "C" void kernel_launch(void* const* d_in, const int* in_sizes, int n_in,
                              void* d_out, int out_size, void* d_ws, size_t ws_size,
                              hipStream_t stream) {
    const float* ctx = (const float*)d_in[0];
    const float* q   = (const float*)d_in[1];
    const float* ker = (const float*)d_in[2];
    float* G = (float*)d_out;

    char* ws = (char*)d_ws;
    unsigned short* qbS   = (unsigned short*)(ws);                 // 1,048,576
    unsigned short* qTS   = (unsigned short*)(ws + 1048576);       // 1,048,576
    unsigned short* cbH   = (unsigned short*)(ws + 2097152);       // 4,194,304
    float*          a     = (float*)(ws + 6291456);                // 65,536
    float*          mfull = (float*)(ws + 6356992);                // 65,536
    float*          hp    = (float*)(ws + 6422528);                // 25,600
    float*          zp    = (float*)(ws + 6448128);                // 256
    float*          Mp    = (float*)(ws + 6448384);                // 256
    const size_t fixed = 6554112;

    int JS = 8;
    if (fixed + 8ull * 3473408ull > ws_size) JS = 4;
    if (fixed + 4ull * 3473408ull > ws_size) JS = 2;

    _Float16* Ub  = (_Float16*)(ws + fixed);
    size_t ubB    = (size_t)JS * 3276800ull;
    float*    mb  = (float*)(ws + fixed + ubB);
    float*    lb  = (float*)(ws + fixed + ubB + (size_t)JS * 65536ull);
    float*    mtb = (float*)(ws + fixed + ubB + (size_t)JS * 131072ull);

    prep_all<<<dim3(128), dim3(256), 0, stream>>>(q, ctx, ker, qbS, qTS, cbH, a);
    attn_main<<<dim3(128, JS), dim3(256), 0, stream>>>(qbS, qTS, cbH, Ub, mb, lb, mtb);

    if (JS == 8) {
        kernel_mf<8><<<dim3(64), dim3(256), 0, stream>>>(a, mtb, mfull, Mp);
        kernel_h<<<dim3(64), dim3(256), 0, stream>>>(mfull, Mp, ctx, hp, zp);
        combine<8><<<dim3(512), dim3(256), 0, stream>>>(Ub, mb, lb, hp, zp, ctx, G);
    } else if (JS == 4) {
        kernel_mf<4><<<dim3(64), dim3(256), 0, stream>>>(a, mtb, mfull, Mp);
        kernel_h<<<dim3(64), dim3(256), 0, stream>>>(mfull, Mp, ctx, hp, zp);
        combine<4><<<dim3(512), dim3(256), 0, stream>>>(Ub, mb, lb, hp, zp, ctx, G);
    } else {
        kernel_mf<2><<<dim3(64), dim3(256), 0, stream>>>(a, mtb, mfull, Mp);
        kernel_h<<<dim3(64), dim3(256), 0, stream>>>(mfull, Mp, ctx, hp, zp);
        combine<2><<<dim3(512), dim3(256), 0, stream>>>(Ub, mb, lb, hp, zp, ctx, G);
    }
}